// Round 19
// baseline (199.039 us; speedup 1.0000x reference)
//
#include <hip/hip_runtime.h>
#include <hip/hip_bf16.h>
#include <math.h>

#define TID threadIdx.x

constexpr int Cc = 512, Tt = 1024, C3 = 1536;

typedef __attribute__((ext_vector_type(8))) __bf16 bf16x8;
typedef __attribute__((ext_vector_type(4))) float f32x4;

__device__ __forceinline__ void async16(const void* g, void* l) {
  __builtin_amdgcn_global_load_lds(
      (const __attribute__((address_space(1))) unsigned int*)g,
      (__attribute__((address_space(3))) unsigned int*)l, 16, 0, 0);
}

__device__ __forceinline__ unsigned int pack2bf(float a, float b) {
  __hip_bfloat162 h;
  h.x = __float2bfloat16(a);
  h.y = __float2bfloat16(b);
  return *reinterpret_cast<unsigned int*>(&h);
}

__device__ __forceinline__ float bf2f(unsigned short u) {
  unsigned int t = ((unsigned int)u) << 16;
  union { unsigned int i; float f; } c;
  c.i = t;
  return c.f;
}

// hardware 2^x (v_exp_f32: D = 2^S0)
__device__ __forceinline__ float exp2_hw(float x) {
  float r;
  asm("v_exp_f32 %0, %1" : "=v"(r) : "v"(x));
  return r;
}

// mish(x) = x * n/(n+2), n = u*(u+2), u = e^x  (one hw exp + one rcp)
__device__ __forceinline__ float mishf(float x) {
  float u = __expf(x);
  float n = u * (u + 2.f);
  float r = x * n * __builtin_amdgcn_rcpf(n + 2.f);
  return (x > 20.f) ? x : r;
}

__device__ __forceinline__ void blockReduce2(float& s, float& ss) {
  #pragma unroll
  for (int off = 32; off > 0; off >>= 1) {
    s  += __shfl_xor(s,  off);
    ss += __shfl_xor(ss, off);
  }
  __shared__ float ls[4], lss[4];
  int w = TID >> 6;
  if ((TID & 63) == 0) { ls[w] = s; lss[w] = ss; }
  __syncthreads();
  s  = ls[0] + ls[1] + ls[2] + ls[3];
  ss = lss[0] + lss[1] + lss[2] + lss[3];
}

// ---------------- zero the raw-stat accumulators (256 floats) ----------------
__global__ void zero_stats(float* p) { p[TID] = 0.f; }

// ---------------- zero the 16-row halo pads of aT[8][1056][512] ----------------
__global__ __launch_bounds__(256) void zero_pads(__hip_bfloat16* __restrict__ aT) {
  int idx = blockIdx.x * 256 + TID;
  int bb = idx >> 11;
  int task = idx & 2047;
  int prow = task >> 6;
  int col = (task & 63) * 8;
  int P = (prow < 16) ? prow : (1024 + prow);
  uint4 z = {0u, 0u, 0u, 0u};
  *reinterpret_cast<uint4*>(aT + ((size_t)bb * 1056 + P) * 512 + col) = z;
}

// ---------------- fused GN(32) + im2col(K=2, pad_lo=0) -> bf16 B1t[b][t][k=2ci+j] ----------------
__global__ __launch_bounds__(256) void gn1_im2col(const float* __restrict__ x,
    const float* __restrict__ w, const float* __restrict__ bv,
    __hip_bfloat16* __restrict__ B1t) {
  __shared__ float hs[16][262];
  int blk = blockIdx.x, bb = blk >> 5, g = blk & 31;
  size_t base = ((size_t)bb * Cc + g * 16) * Tt;
  const float* xp = x + base;
  float s = 0.f, ss = 0.f;
  for (int i = TID * 4; i < 16 * Tt; i += 1024) {
    float4 v = *reinterpret_cast<const float4*>(xp + i);
    s  += v.x + v.y + v.z + v.w;
    ss += v.x * v.x + v.y * v.y + v.z * v.z + v.w * v.w;
  }
  blockReduce2(s, ss);
  float mean = s * (1.f / 16384.f);
  float rstd = rsqrtf(ss * (1.f / 16384.f) - mean * mean + 1e-5f);

  char* ob = reinterpret_cast<char*>(B1t + (size_t)bb * Tt * 1024 + g * 32);
  for (int tc = 0; tc < 4; ++tc) {
    int tbase = tc * 256;
    __syncthreads();
    for (int task = TID; task < 1024; task += 256) {
      int row = task >> 6, c4 = task & 63;
      int ch = g * 16 + row;
      float sw = w[ch] * rstd;
      float sb = bv[ch] - mean * sw;
      float4 v = *reinterpret_cast<const float4*>(xp + (size_t)row * Tt + tbase + c4 * 4);
      hs[row][c4 * 4 + 0] = v.x * sw + sb;
      hs[row][c4 * 4 + 1] = v.y * sw + sb;
      hs[row][c4 * 4 + 2] = v.z * sw + sb;
      hs[row][c4 * 4 + 3] = v.w * sw + sb;
    }
    if (TID < 16) {
      int row = TID, t = tbase + 256;
      float val = 0.f;
      if (t < Tt) {
        int ch = g * 16 + row;
        float sw = w[ch] * rstd;
        float sb = bv[ch] - mean * sw;
        val = xp[(size_t)row * Tt + t] * sw + sb;
      }
      hs[row][256] = val;
    }
    __syncthreads();
    for (int task = TID; task < 1024; task += 256) {
      int t = task >> 2, cj = task & 3;
      int ci = cj * 4;
      uint4 u;
      u.x = pack2bf(hs[ci + 0][t], hs[ci + 0][t + 1]);
      u.y = pack2bf(hs[ci + 1][t], hs[ci + 1][t + 1]);
      u.z = pack2bf(hs[ci + 2][t], hs[ci + 2][t + 1]);
      u.w = pack2bf(hs[ci + 3][t], hs[ci + 3][t + 1]);
      *reinterpret_cast<uint4*>(ob + ((size_t)(tbase + t) * 1024 + cj * 8) * 2) = u;
    }
  }
}

// ---------------- f32 -> bf16 cast (weights) ----------------
__global__ __launch_bounds__(256) void cast_bf16(const float* __restrict__ in,
    __hip_bfloat16* __restrict__ out, int n) {
  int i = (blockIdx.x * 256 + TID) * 4;
  if (i >= n) return;
  float4 v = *reinterpret_cast<const float4*>(in + i);
  *reinterpret_cast<unsigned int*>(out + i)     = pack2bf(v.x, v.y);
  *reinterpret_cast<unsigned int*>(out + i + 2) = pack2bf(v.z, v.w);
}

// ---------------- wproj [o][ci][4] f32 -> A2[j][o][ci] bf16 ----------------
__global__ __launch_bounds__(256) void cast_wproj(const float* __restrict__ wp,
    __hip_bfloat16* __restrict__ A2) {
  int o = blockIdx.x;
  int ci = TID * 2;
  float4 v0 = *reinterpret_cast<const float4*>(wp + ((size_t)o * 512 + ci) * 4);
  float4 v1 = *reinterpret_cast<const float4*>(wp + ((size_t)o * 512 + ci + 1) * 4);
  const float* a0 = &v0.x;
  const float* a1 = &v1.x;
  #pragma unroll
  for (int j = 0; j < 4; ++j) {
    unsigned int u = pack2bf(a0[j], a1[j]);
    *reinterpret_cast<unsigned int*>(A2 + ((size_t)j * 512 + o) * 512 + ci) = u;
  }
}

// ---------------- bf16 MFMA GEMM v12: A register-prefetched (no DMA), B LDS issue-ahead dbuf --
// BM=192 x BN=256, 1024 thr, 16 waves 4Mx4N. DMA bytes halved vs v11 (B only, 32KB/step).
__global__ __launch_bounds__(1024, 4) void gemm_bt12(const __hip_bfloat16* __restrict__ A,
    const __hip_bfloat16* __restrict__ Bt, const float* __restrict__ bias,
    __hip_bfloat16* __restrict__ Cout, float* __restrict__ statraw) {
  constexpr int K = 1024;
  constexpr int BUF = 32 * 1024;
  __shared__ __align__(16) char lds[2 * BUF];   // 64 KB (B only)
  int bz = blockIdx.x & 7;
  int inner = blockIdx.x >> 3;
  int t0 = (inner & 3) * 256;
  int og = inner >> 2;
  int o0 = og * 192;
  int wave = TID >> 6, lane = TID & 63;
  int l4 = lane >> 4, r15 = lane & 15;
  int wm = wave >> 2, wn = wave & 3;
  const __hip_bfloat16* Bb = Bt + ((size_t)bz * 1024 + t0) * K;
  const __hip_bfloat16* Arow0 = A + (size_t)(o0 + (wm * 3 + 0) * 16 + r15) * K + l4 * 8;
  const __hip_bfloat16* Arow1 = A + (size_t)(o0 + (wm * 3 + 1) * 16 + r15) * K + l4 * 8;
  const __hip_bfloat16* Arow2 = A + (size_t)(o0 + (wm * 3 + 2) * 16 + r15) * K + l4 * 8;

  f32x4 acc[3][4];
  f32x4 zz = {0.f, 0.f, 0.f, 0.f};
  #pragma unroll
  for (int m = 0; m < 3; ++m)
    #pragma unroll
    for (int n = 0; n < 4; ++n) acc[m][n] = zz;

  auto stageB = [&](int kt, int buf) {
    char* dst = lds + buf * BUF;
    #pragma unroll
    for (int c = 0; c < 2; ++c) {
      int ch = c * 16 + wave;                     // 0..31 B-chunks of 1KB
      int row = (ch >> 1) * 16 + r15;
      int kof = kt * 64 + (ch & 1) * 32 + l4 * 8;
      async16(Bb + (size_t)row * K + kof, dst + ch * 1024 + lane * 16);
    }
  };

  bf16x8 afA[6], afB[6];
  auto loadA = [&](int kt, bf16x8* af) {
    af[0] = *reinterpret_cast<const bf16x8*>(Arow0 + kt * 64);
    af[1] = *reinterpret_cast<const bf16x8*>(Arow0 + kt * 64 + 32);
    af[2] = *reinterpret_cast<const bf16x8*>(Arow1 + kt * 64);
    af[3] = *reinterpret_cast<const bf16x8*>(Arow1 + kt * 64 + 32);
    af[4] = *reinterpret_cast<const bf16x8*>(Arow2 + kt * 64);
    af[5] = *reinterpret_cast<const bf16x8*>(Arow2 + kt * 64 + 32);
  };
  auto compute = [&](char* cur, const bf16x8* af) {
    #pragma unroll
    for (int kk = 0; kk < 2; ++kk) {
      bf16x8 bfr[4];
      #pragma unroll
      for (int n = 0; n < 4; ++n)
        bfr[n] = *reinterpret_cast<const bf16x8*>(cur + (((wn * 4 + n) * 2 + kk)) * 1024 + lane * 16);
      #pragma unroll
      for (int m = 0; m < 3; ++m)
        #pragma unroll
        for (int n = 0; n < 4; ++n)
          acc[m][n] = __builtin_amdgcn_mfma_f32_16x16x32_bf16(af[m * 2 + kk], bfr[n], acc[m][n], 0, 0, 0);
    }
  };

  loadA(0, afA);
  stageB(0, 0);
  __syncthreads();
  #pragma unroll 1
  for (int kt = 0; kt < 16; kt += 2) {
    if (kt + 1 < 16) { stageB(kt + 1, 1); loadA(kt + 1, afB); }
    compute(lds, afA);
    __syncthreads();
    if (kt + 2 < 16) { stageB(kt + 2, 0); loadA(kt + 2, afA); }
    compute(lds + BUF, afB);
    __syncthreads();
  }

  // epilogue: bf16 store (+bias); block covers exactly one GN group (192 rows)
  float* sred = reinterpret_cast<float*>(lds);
  #pragma unroll
  for (int m = 0; m < 3; ++m) {
    float s = 0.f, ss2 = 0.f;
    #pragma unroll
    for (int n = 0; n < 4; ++n) {
      int ocol = t0 + (wn * 4 + n) * 16 + r15;
      #pragma unroll
      for (int r = 0; r < 4; ++r) {
        int orow = o0 + (wm * 3 + m) * 16 + l4 * 4 + r;
        float v = acc[m][n][r] + bias[orow];
        Cout[((size_t)bz * C3 + orow) * 1024 + ocol] = __float2bfloat16(v);
        s += v;
        ss2 += v * v;
      }
    }
    #pragma unroll
    for (int off = 1; off < 64; off <<= 1) {
      s   += __shfl_xor(s, off);
      ss2 += __shfl_xor(ss2, off);
    }
    if (lane == 0) {
      sred[(wave * 3 + m) * 2]     = s;
      sred[(wave * 3 + m) * 2 + 1] = ss2;
    }
  }
  __syncthreads();
  if (TID == 0) {
    float S = 0.f, SS = 0.f;
    #pragma unroll
    for (int slot = 0; slot < 48; ++slot) {
      S  += sred[slot * 2];
      SS += sred[slot * 2 + 1];
    }
    int g = bz * 8 + og;
    atomicAdd(&statraw[2 * g],     S);
    atomicAdd(&statraw[2 * g + 1], SS);
  }
}

// ---------------- shift-conv GEMM (conv K=4), batch-per-XCD affinity grid (R18-proven) --------
__global__ __launch_bounds__(256) void gemm_c4b(const __hip_bfloat16* __restrict__ A2,
    const __hip_bfloat16* __restrict__ aT, const float* __restrict__ bias,
    float* __restrict__ Cout, float* __restrict__ statraw) {
  constexpr int BUF = 42 * 1024;
  __shared__ __align__(16) char lds[2 * BUF];
  int bz = blockIdx.x & 7;
  int inner = blockIdx.x >> 3;
  int t0 = (inner & 7) * 128;
  int o0 = (inner >> 3) * 128;
  int wave = TID >> 6, lane = TID & 63;
  int l4 = lane >> 4, r15 = lane & 15;
  int wm = wave >> 1, wn = wave & 1;
  const __hip_bfloat16* aTb = aT + (size_t)bz * 1056 * 512;

  f32x4 acc[4][4];
  f32x4 zz = {0.f, 0.f, 0.f, 0.f};
  #pragma unroll
  for (int m = 0; m < 4; ++m)
    #pragma unroll
    for (int n = 0; n < 4; ++n) acc[m][n] = zz;

  auto stage = [&](int kt, int buf) {
    char* dst = lds + buf * BUF;
    #pragma unroll
    for (int c = 0; c < 11; ++c) {
      int ch = c * 4 + wave;
      if (ch < 42) {
        const __hip_bfloat16* src;
        if (ch < 32) {
          int j = ch >> 3, rg = ch & 7;
          src = A2 + ((size_t)j * 512 + o0 + rg * 16 + r15) * 512 + kt * 32 + l4 * 8;
        } else {
          int rg = ch - 32;
          src = aTb + (size_t)(t0 + rg * 16 + r15) * 512 + kt * 32 + l4 * 8;
        }
        async16(src, dst + ch * 1024 + lane * 16);
      }
    }
  };

  stage(0, 0);
  __syncthreads();
  for (int kt = 0; kt < 16; ++kt) {
    if (kt + 1 < 16) stage(kt + 1, (kt + 1) & 1);
    char* cur = lds + (kt & 1) * BUF;
    #pragma unroll
    for (int j = 0; j < 4; ++j) {
      bf16x8 af[4], bfr[4];
      #pragma unroll
      for (int m = 0; m < 4; ++m)
        af[m] = *reinterpret_cast<const bf16x8*>(cur + (j * 8 + wm * 4 + m) * 1024 + lane * 16);
      #pragma unroll
      for (int n = 0; n < 4; ++n) {
        int q = (wn * 4 + n) * 16 + r15 + j + 15;
        bfr[n] = *reinterpret_cast<const bf16x8*>(cur + 32 * 1024 + (q >> 4) * 1024 + l4 * 256 + (q & 15) * 16);
      }
      #pragma unroll
      for (int m = 0; m < 4; ++m)
        #pragma unroll
        for (int n = 0; n < 4; ++n)
          acc[m][n] = __builtin_amdgcn_mfma_f32_16x16x32_bf16(af[m], bfr[n], acc[m][n], 0, 0, 0);
    }
    __syncthreads();
  }

  float* sred = reinterpret_cast<float*>(lds);
  #pragma unroll
  for (int m = 0; m < 4; ++m) {
    float s = 0.f, ss2 = 0.f;
    #pragma unroll
    for (int n = 0; n < 4; ++n) {
      int ocol = t0 + (wn * 4 + n) * 16 + r15;
      #pragma unroll
      for (int r = 0; r < 4; ++r) {
        int orow = o0 + (wm * 4 + m) * 16 + l4 * 4 + r;
        float v = acc[m][n][r] + bias[orow];
        Cout[((size_t)bz * Cc + orow) * 1024 + ocol] = v;
        s += v;
        ss2 += v * v;
      }
    }
    #pragma unroll
    for (int off = 1; off < 64; off <<= 1) {
      s   += __shfl_xor(s, off);
      ss2 += __shfl_xor(ss2, off);
    }
    if (lane == 0) {
      sred[(wave * 4 + m) * 2]     = s;
      sred[(wave * 4 + m) * 2 + 1] = ss2;
    }
  }
  __syncthreads();
  if (TID < 2) {
    int g0 = o0 >> 6;
    float S = 0.f, SS = 0.f;
    int cnt = 0;
    #pragma unroll
    for (int slot = 0; slot < 16; ++slot) {
      int rc = ((slot >> 3) << 2) + (slot & 3);
      int g = (o0 + rc * 16) >> 6;
      if (g == g0 + (int)TID) {
        S  += sred[slot * 2];
        SS += sred[slot * 2 + 1];
        ++cnt;
      }
    }
    if (cnt) {
      atomicAdd(&statraw[2 * (bz * 8 + g0 + TID)],     S);
      atomicAdd(&statraw[2 * (bz * 8 + g0 + TID) + 1], SS);
    }
  }
}

// ---------------- fused GN(8)+Mish + build attn input images (bf16 qkv input, raw stats) ----------------
__global__ __launch_bounds__(256) void gn2_prep(const __hip_bfloat16* __restrict__ qkv,
    const float* __restrict__ straw, const float* __restrict__ w, const float* __restrict__ bv,
    char* __restrict__ qTp, char* __restrict__ kimg, char* __restrict__ vimg) {
  __shared__ unsigned short hbf[192 * 66];
  int tl = blockIdx.x & 15, hb = blockIdx.x >> 4;
  int b = hb >> 3, hd = hb & 7;
  float rs = straw[2 * (b * 8 + hd)], rq = straw[2 * (b * 8 + hd) + 1];
  float mean = rs * (1.f / 196608.f);
  float rstd = rsqrtf(fmaxf(rq * (1.f / 196608.f) - mean * mean, 0.f) + 1e-5f);
  for (int task = TID; task < 768; task += 256) {
    int row = task >> 2, seg = task & 3;
    int ch = hd * 192 + row;
    float sw = w[ch] * rstd;
    float sb = bv[ch] - mean * sw;
    const uint4* src = reinterpret_cast<const uint4*>(
        qkv + ((size_t)(b * C3 + ch)) * 1024 + tl * 64 + seg * 16);
    uint4 u0 = src[0], u1 = src[1];
    unsigned int uu[8] = {u0.x, u0.y, u0.z, u0.w, u1.x, u1.y, u1.z, u1.w};
    unsigned int* dst = reinterpret_cast<unsigned int*>(&hbf[row * 66 + seg * 16]);
    #pragma unroll
    for (int j = 0; j < 8; ++j) {
      float a = mishf(bf2f((unsigned short)(uu[j] & 0xffff)) * sw + sb);
      float c = mishf(bf2f((unsigned short)(uu[j] >> 16)) * sw + sb);
      dst[j] = pack2bf(a, c);
    }
  }
  __syncthreads();
  size_t tileof = ((size_t)hb * 16 + tl) * 8192;
  {
    int t = TID & 63, sel = TID >> 6;
    int img = sel >> 1, half = sel & 1;
    char* obase = (img == 0 ? qTp : kimg) + tileof + (size_t)t * 128;
    #pragma unroll
    for (int cc = 0; cc < 4; ++cc) {
      int chunk = half * 4 + cc;
      uint4 u;
      unsigned int* up = reinterpret_cast<unsigned int*>(&u);
      #pragma unroll
      for (int j = 0; j < 4; ++j) {
        int c = chunk * 8 + j * 2;
        unsigned int lo = hbf[(img * 64 + c) * 66 + t];
        unsigned int hi = hbf[(img * 64 + c + 1) * 66 + t];
        up[j] = lo | (hi << 16);
      }
      int cpos = (img == 0) ? chunk : (chunk ^ (t & 7));
      *reinterpret_cast<uint4*>(obase + cpos * 16) = u;
    }
  }
  {
    int c = TID & 63, qtr = TID >> 6;
    const unsigned int* vrow = reinterpret_cast<const unsigned int*>(&hbf[(128 + c) * 66]);
    char* obase = vimg + tileof + (size_t)c * 128;
    #pragma unroll
    for (int k = 0; k < 2; ++k) {
      int chunk = qtr * 2 + k;
      uint4 u;
      unsigned int* up = reinterpret_cast<unsigned int*>(&u);
      #pragma unroll
      for (int j = 0; j < 4; ++j) up[j] = vrow[chunk * 4 + j];
      *reinterpret_cast<uint4*>(obase + (chunk ^ (c & 7)) * 16) = u;
    }
  }
}

// ---------------- MFMA flash attention v6: KVBLK=128 (R17-proven) ----------------
__global__ __launch_bounds__(1024) void attn_mfma6(const char* __restrict__ qTp,
    const char* __restrict__ kimg, const char* __restrict__ vimg,
    __hip_bfloat16* __restrict__ aT) {
  __shared__ __align__(16) char smem[131072];
  char* kbuf0 = smem;
  char* kbuf1 = smem + 16384;
  char* vbuf0 = smem + 32768;
  char* vbuf1 = smem + 49152;
  char* pp    = smem + 65536;  // 16 waves x 4KB
  char* ov    = smem;          // 32KB alias (dead K/V buffers)

  int hb = blockIdx.y;
  int b = hb >> 3, hd = hb & 7;
  int lane = TID & 63, wave = TID >> 6;
  int qt = wave >> 2, qw = wave & 3;
  int l4 = lane >> 4, r15 = lane & 15;
  size_t ibase = (size_t)hb * 16 * 8192;
  const char* ksrc = kimg + ibase;
  const char* vsrc = vimg + ibase;

  async16(ksrc + (size_t)TID * 16, kbuf0 + (size_t)TID * 16);
  async16(vsrc + (size_t)TID * 16, vbuf0 + (size_t)TID * 16);

  bf16x8 aq[2];
  int tg = qw * 16 + r15;
  const char* qrow = qTp + ibase + (size_t)(blockIdx.x * 4 + qt) * 8192 + (size_t)tg * 128;
  aq[0] = *reinterpret_cast<const bf16x8*>(qrow + l4 * 16);
  aq[1] = *reinterpret_cast<const bf16x8*>(qrow + 64 + l4 * 16);
  {
    const float SC = 0.125f * 1.44269504f;
    #pragma unroll
    for (int kk = 0; kk < 2; ++kk) {
      unsigned int* u = reinterpret_cast<unsigned int*>(&aq[kk]);
      #pragma unroll
      for (int j = 0; j < 4; ++j) {
        float lo = bf2f((unsigned short)(u[j] & 0xffff)) * SC;
        float hi = bf2f((unsigned short)(u[j] >> 16)) * SC;
        u[j] = pack2bf(lo, hi);
      }
    }
  }

  f32x4 osum[4];
  f32x4 zz = {0.f, 0.f, 0.f, 0.f};
  #pragma unroll
  for (int cf = 0; cf < 4; ++cf) osum[cf] = zz;
  float mrow[4] = {-1e30f, -1e30f, -1e30f, -1e30f};
  float lrow[4] = {0.f, 0.f, 0.f, 0.f};
  __syncthreads();

  for (int it = 0; it < 8; ++it) {
    char* kcur = (it & 1) ? kbuf1 : kbuf0;
    char* vcur = (it & 1) ? vbuf1 : vbuf0;
    if (it < 7) {
      char* knxt = (it & 1) ? kbuf0 : kbuf1;
      char* vnxt = (it & 1) ? vbuf0 : vbuf1;
      const char* kn = ksrc + (size_t)(it + 1) * 16384;
      const char* vn = vsrc + (size_t)(it + 1) * 16384;
      async16(kn + (size_t)TID * 16, knxt + (size_t)TID * 16);
      async16(vn + (size_t)TID * 16, vnxt + (size_t)TID * 16);
    }
    f32x4 sc[8];
    #pragma unroll
    for (int sf = 0; sf < 8; ++sf) sc[sf] = zz;
    #pragma unroll
    for (int sf = 0; sf < 8; ++sf) {
      int sr = sf * 16 + r15;
      #pragma unroll
      for (int kk = 0; kk < 2; ++kk) {
        bf16x8 bk = *reinterpret_cast<const bf16x8*>(kcur + sr * 128 + (((kk * 4 + l4) ^ (sr & 7)) << 4));
        sc[sf] = __builtin_amdgcn_mfma_f32_16x16x32_bf16(aq[kk], bk, sc[sf], 0, 0, 0);
      }
    }
    float tmax[4];
    #pragma unroll
    for (int r = 0; r < 4; ++r) {
      float m0 = fmaxf(fmaxf(sc[0][r], sc[1][r]), fmaxf(sc[2][r], sc[3][r]));
      float m1 = fmaxf(fmaxf(sc[4][r], sc[5][r]), fmaxf(sc[6][r], sc[7][r]));
      tmax[r] = fmaxf(m0, m1);
    }
    #pragma unroll
    for (int off = 1; off < 16; off <<= 1)
      #pragma unroll
      for (int r = 0; r < 4; ++r) tmax[r] = fmaxf(tmax[r], __shfl_xor(tmax[r], off));
    bool grow = (tmax[0] > mrow[0]) | (tmax[1] > mrow[1]) |
                (tmax[2] > mrow[2]) | (tmax[3] > mrow[3]);
    if (grow) {
      float alpha[4];
      #pragma unroll
      for (int r = 0; r < 4; ++r) {
        float mnew = fmaxf(mrow[r], tmax[r]);
        alpha[r] = exp2_hw(mrow[r] - mnew);
        mrow[r] = mnew;
        lrow[r] *= alpha[r];
      }
      #pragma unroll
      for (int cf = 0; cf < 4; ++cf)
        #pragma unroll
        for (int r = 0; r < 4; ++r) osum[cf][r] *= alpha[r];
    }
    char* pw = pp + wave * 4096;
    float psum[4] = {0.f, 0.f, 0.f, 0.f};
    #pragma unroll
    for (int sf = 0; sf < 8; ++sf) {
      int s = sf * 16 + r15;
      int chunk = s >> 3;
      #pragma unroll
      for (int r = 0; r < 4; ++r) {
        float p = exp2_hw(sc[sf][r] - mrow[r]);
        psum[r] += p;
        int tlc = l4 * 4 + r;
        *reinterpret_cast<__hip_bfloat16*>(pw + tlc * 256 + (((chunk ^ (tlc & 15)) << 4) | ((s & 7) * 2)))
            = __float2bfloat16(p);
      }
    }
    #pragma unroll
    for (int r = 0; r < 4; ++r) lrow[r] += psum[r];
    asm volatile("s_waitcnt lgkmcnt(0)" ::: "memory");
    __builtin_amdgcn_sched_barrier(0);

    bf16x8 pa[4];
    #pragma unroll
    for (int kk2 = 0; kk2 < 4; ++kk2)
      pa[kk2] = *reinterpret_cast<const bf16x8*>(pw + r15 * 256 + (((kk2 * 4 + l4) ^ (r15 & 15)) << 4));
    #pragma unroll
    for (int cf = 0; cf < 4; ++cf) {
      int cr = cf * 16 + r15;
      #pragma unroll
      for (int kk2 = 0; kk2 < 4; ++kk2) {
        bf16x8 bv = *reinterpret_cast<const bf16x8*>(vcur + (kk2 >> 1) * 8192 + cr * 128 +
                                                     ((((kk2 & 1) * 4 + l4) ^ (cr & 7)) << 4));
        osum[cf] = __builtin_amdgcn_mfma_f32_16x16x32_bf16(pa[kk2], bv, osum[cf], 0, 0, 0);
      }
    }
    __syncthreads();
  }

  #pragma unroll
  for (int off = 1; off < 16; off <<= 1)
    #pragma unroll
    for (int r = 0; r < 4; ++r) lrow[r] += __shfl_xor(lrow[r], off);
  float linv[4];
  #pragma unroll
  for (int r = 0; r < 4; ++r) linv[r] = 1.f / lrow[r];

  #pragma unroll
  for (int cf = 0; cf < 4; ++cf) {
    int c = cf * 16 + r15;
    #pragma unroll
    for (int r = 0; r < 4; ++r) {
      int t = qt * 64 + qw * 16 + l4 * 4 + r;
      *reinterpret_cast<__hip_bfloat16*>(ov + t * 128 + ((((c >> 3) ^ (t & 7)) << 4) | ((c & 7) * 2)))
          = __float2bfloat16(osum[cf][r] * linv[r]);
    }
  }
  __syncthreads();
  __hip_bfloat16* ap = aT + ((size_t)b * 1056 + 16 + blockIdx.x * 256) * 512 + hd * 64;
  for (int u = TID; u < 2048; u += 1024) {
    int t = u >> 3, cj = u & 7;
    uint4 o4 = *reinterpret_cast<const uint4*>(ov + t * 128 + ((cj ^ (t & 7)) << 4));
    *reinterpret_cast<uint4*>(ap + (size_t)t * 512 + cj * 8) = o4;
  }
}

// ---------------- final: out = x + mish(gn(y2)) in-place on d_out (raw stats) ----------------
__global__ __launch_bounds__(256) void final_kernel(const float* __restrict__ x,
    float* __restrict__ y, const float* __restrict__ straw,
    const float* __restrict__ w, const float* __restrict__ bv) {
  size_t i = ((size_t)blockIdx.x * 256 + TID) * 4;
  int ch = (int)((i >> 10) & (Cc - 1));
  int b = (int)(i >> 19);
  int g = b * 8 + (ch >> 6);
  float rs = straw[2 * g], rq = straw[2 * g + 1];
  float mean = rs * (1.f / 65536.f);
  float rstd = rsqrtf(fmaxf(rq * (1.f / 65536.f) - mean * mean, 0.f) + 1e-5f);
  float sw = w[ch] * rstd;
  float sb = bv[ch] - mean * sw;
  float4 v  = *reinterpret_cast<const float4*>(y + i);
  float4 xv = *reinterpret_cast<const float4*>(x + i);
  v.x = xv.x + mishf(v.x * sw + sb);
  v.y = xv.y + mishf(v.y * sw + sb);
  v.z = xv.z + mishf(v.z * sw + sb);
  v.w = xv.w + mishf(v.w * sw + sb);
  *reinterpret_cast<float4*>(y + i) = v;
}

extern "C" void kernel_launch(void* const* d_in, const int* in_sizes, int n_in,
                              void* d_out, int out_size, void* d_ws, size_t ws_size,
                              hipStream_t stream) {
  const float* x     = (const float*)d_in[0];
  const float* gn_w  = (const float*)d_in[1];
  const float* gn_b  = (const float*)d_in[2];
  const float* wqkv  = (const float*)d_in[3];
  const float* bqkv  = (const float*)d_in[4];
  const float* gnq_w = (const float*)d_in[5];
  const float* gnq_b = (const float*)d_in[6];
  const float* wproj = (const float*)d_in[7];
  const float* bproj = (const float*)d_in[8];
  const float* gnp_w = (const float*)d_in[9];
  const float* gnp_b = (const float*)d_in[10];
  float* out = (float*)d_out;

  char* ws = (char*)d_ws;
  const size_t MB = 1024 * 1024;
  __hip_bfloat16* qkvb = (__hip_bfloat16*)ws;            // [0,24MB)   step5 -> step6
  __hip_bfloat16* aT   = (__hip_bfloat16*)(ws + 24 * MB);// [24,33MB)  step2/7 -> step9
  __hip_bfloat16* A1   = (__hip_bfloat16*)(ws + 56 * MB);// [56,59MB)  step3 -> step5
  char* vimg = ws + 56 * MB;                             // [56,64MB)  step6 -> step7 (A1 dead)
  __hip_bfloat16* A2   = (__hip_bfloat16*)(ws + 56 * MB);// [56,58MB)  step8 -> step9 (vimg dead)
  float* st2raw = (float*)(ws + 64 * MB);
  float* st3raw = st2raw + 128;
  __hip_bfloat16* B1t = (__hip_bfloat16*)d_out;          // d_out as B1t  step4 -> step5
  char* qTp  = (char*)d_out;                             // d_out[0,8MB)  step6 -> step7
  char* kimg = (char*)d_out + 8 * MB;                    // d_out[8,16MB) step6 -> step7

  dim3 blk(256);
  zero_stats<<<1, blk, 0, stream>>>(st2raw);                                        // 1
  zero_pads<<<64, blk, 0, stream>>>(aT);                                            // 2
  cast_bf16<<<1536, blk, 0, stream>>>(wqkv, A1, C3 * 1024);                         // 3
  gn1_im2col<<<256, blk, 0, stream>>>(x, gn_w, gn_b, B1t);                          // 4
  gemm_bt12<<<256, dim3(1024), 0, stream>>>(A1, B1t, bqkv, qkvb, st2raw);           // 5
  gn2_prep<<<1024, blk, 0, stream>>>(qkvb, st2raw, gnq_w, gnq_b, qTp, kimg, vimg);  // 6
  attn_mfma6<<<dim3(4, 64), dim3(1024), 0, stream>>>(qTp, kimg, vimg, aT);          // 7
  cast_wproj<<<512, blk, 0, stream>>>(wproj, A2);                                   // 8
  gemm_c4b<<<256, blk, 0, stream>>>(A2, aT, bproj, out, st3raw);                    // 9
  final_kernel<<<4096, blk, 0, stream>>>(x, out, st3raw, gnp_w, gnp_b);             // 10
}

// Round 21
// 155.482 us; speedup vs baseline: 1.2801x; 1.2801x over previous
//
#include <hip/hip_runtime.h>
#include <hip/hip_bf16.h>
#include <math.h>

#define TID threadIdx.x

constexpr int Cc = 512, Tt = 1024, C3 = 1536;

typedef __attribute__((ext_vector_type(8))) __bf16 bf16x8;
typedef __attribute__((ext_vector_type(4))) float f32x4;

__device__ __forceinline__ void async16(const void* g, void* l) {
  __builtin_amdgcn_global_load_lds(
      (const __attribute__((address_space(1))) unsigned int*)g,
      (__attribute__((address_space(3))) unsigned int*)l, 16, 0, 0);
}

__device__ __forceinline__ unsigned int pack2bf(float a, float b) {
  __hip_bfloat162 h;
  h.x = __float2bfloat16(a);
  h.y = __float2bfloat16(b);
  return *reinterpret_cast<unsigned int*>(&h);
}

__device__ __forceinline__ float bf2f(unsigned short u) {
  unsigned int t = ((unsigned int)u) << 16;
  union { unsigned int i; float f; } c;
  c.i = t;
  return c.f;
}

// hardware 2^x (v_exp_f32: D = 2^S0)
__device__ __forceinline__ float exp2_hw(float x) {
  float r;
  asm("v_exp_f32 %0, %1" : "=v"(r) : "v"(x));
  return r;
}

// mish(x) = x * n/(n+2), n = u*(u+2), u = e^x  (one hw exp + one rcp)
__device__ __forceinline__ float mishf(float x) {
  float u = __expf(x);
  float n = u * (u + 2.f);
  float r = x * n * __builtin_amdgcn_rcpf(n + 2.f);
  return (x > 20.f) ? x : r;
}

__device__ __forceinline__ void blockReduce2(float& s, float& ss) {
  #pragma unroll
  for (int off = 32; off > 0; off >>= 1) {
    s  += __shfl_xor(s,  off);
    ss += __shfl_xor(ss, off);
  }
  __shared__ float ls[4], lss[4];
  int w = TID >> 6;
  if ((TID & 63) == 0) { ls[w] = s; lss[w] = ss; }
  __syncthreads();
  s  = ls[0] + ls[1] + ls[2] + ls[3];
  ss = lss[0] + lss[1] + lss[2] + lss[3];
}

// ---------------- zero the raw-stat accumulators (256 floats) ----------------
__global__ void zero_stats(float* p) { p[TID] = 0.f; }

// ---------------- zero the 16-row halo pads of a padded [8][1056][512] bf16 tensor ----------------
__global__ __launch_bounds__(256) void zero_pads(__hip_bfloat16* __restrict__ aT) {
  int idx = blockIdx.x * 256 + TID;
  int bb = idx >> 11;
  int task = idx & 2047;
  int prow = task >> 6;
  int col = (task & 63) * 8;
  int P = (prow < 16) ? prow : (1024 + prow);
  uint4 z = {0u, 0u, 0u, 0u};
  *reinterpret_cast<uint4*>(aT + ((size_t)bb * 1056 + P) * 512 + col) = z;
}

// ---------------- fused GN(32) -> bf16 hT[b][16+t][ci] (transposed, padded, NO im2col dup) ----
__global__ __launch_bounds__(256) void gn1_hT(const float* __restrict__ x,
    const float* __restrict__ w, const float* __restrict__ bv,
    __hip_bfloat16* __restrict__ hT) {
  __shared__ float hs[16][262];
  int blk = blockIdx.x, bb = blk >> 5, g = blk & 31;
  size_t base = ((size_t)bb * Cc + g * 16) * Tt;
  const float* xp = x + base;
  float s = 0.f, ss = 0.f;
  for (int i = TID * 4; i < 16 * Tt; i += 1024) {
    float4 v = *reinterpret_cast<const float4*>(xp + i);
    s  += v.x + v.y + v.z + v.w;
    ss += v.x * v.x + v.y * v.y + v.z * v.z + v.w * v.w;
  }
  blockReduce2(s, ss);
  float mean = s * (1.f / 16384.f);
  float rstd = rsqrtf(ss * (1.f / 16384.f) - mean * mean + 1e-5f);

  __hip_bfloat16* ob = hT + (size_t)bb * 1056 * 512 + g * 16;
  for (int tc = 0; tc < 4; ++tc) {
    int tbase = tc * 256;
    __syncthreads();
    for (int task = TID; task < 1024; task += 256) {
      int row = task >> 6, c4 = task & 63;
      int ch = g * 16 + row;
      float sw = w[ch] * rstd;
      float sb = bv[ch] - mean * sw;
      float4 v = *reinterpret_cast<const float4*>(xp + (size_t)row * Tt + tbase + c4 * 4);
      hs[row][c4 * 4 + 0] = v.x * sw + sb;
      hs[row][c4 * 4 + 1] = v.y * sw + sb;
      hs[row][c4 * 4 + 2] = v.z * sw + sb;
      hs[row][c4 * 4 + 3] = v.w * sw + sb;
    }
    __syncthreads();
    for (int task = TID; task < 512; task += 256) {
      int t = task >> 1, half = task & 1;
      int c0 = half * 8;
      uint4 u;
      u.x = pack2bf(hs[c0 + 0][t], hs[c0 + 1][t]);
      u.y = pack2bf(hs[c0 + 2][t], hs[c0 + 3][t]);
      u.z = pack2bf(hs[c0 + 4][t], hs[c0 + 5][t]);
      u.w = pack2bf(hs[c0 + 6][t], hs[c0 + 7][t]);
      *reinterpret_cast<uint4*>(ob + (size_t)(16 + tbase + t) * 512 + c0) = u;
    }
  }
}

// ---------------- wqkv [o][ci][2] f32 -> A1s[j][o][ci] bf16 (2 planes of 1536x512) ----------------
__global__ __launch_bounds__(256) void cast_wqkv(const float* __restrict__ wq,
    __hip_bfloat16* __restrict__ A1s) {
  int o = blockIdx.x;
  int ci = TID * 2;
  float4 v = *reinterpret_cast<const float4*>(wq + ((size_t)o * 512 + ci) * 2);
  unsigned int u0 = pack2bf(v.x, v.z);   // tap j=0: ci, ci+1
  unsigned int u1 = pack2bf(v.y, v.w);   // tap j=1
  *reinterpret_cast<unsigned int*>(A1s + (size_t)o * 512 + ci) = u0;
  *reinterpret_cast<unsigned int*>(A1s + ((size_t)1536 + o) * 512 + ci) = u1;
}

// ---------------- wproj [o][ci][4] f32 -> A2[j][o][ci] bf16 ----------------
__global__ __launch_bounds__(256) void cast_wproj(const float* __restrict__ wp,
    __hip_bfloat16* __restrict__ A2) {
  int o = blockIdx.x;
  int ci = TID * 2;
  float4 v0 = *reinterpret_cast<const float4*>(wp + ((size_t)o * 512 + ci) * 4);
  float4 v1 = *reinterpret_cast<const float4*>(wp + ((size_t)o * 512 + ci + 1) * 4);
  const float* a0 = &v0.x;
  const float* a1 = &v1.x;
  #pragma unroll
  for (int j = 0; j < 4; ++j) {
    unsigned int u = pack2bf(a0[j], a1[j]);
    *reinterpret_cast<unsigned int*>(A2 + ((size_t)j * 512 + o) * 512 + ci) = u;
  }
}

// ---------------- shift-conv GEMM for conv K=2 (gemm1): BM=192 x BN=256, 1024 thr ------------
// y[b][o][t] = sum_j sum_ci A1s[j][o][ci] * hT[b][16+t+j][ci] + bias[o]
// LDS/step: 24 A-chunks (2 planes x 12 rowgrp) + 17 B-chunks (272-row window) = 41KB; dbuf.
__global__ __launch_bounds__(1024, 4) void gemm_s2(const __hip_bfloat16* __restrict__ A1s,
    const __hip_bfloat16* __restrict__ hT, const float* __restrict__ bias,
    __hip_bfloat16* __restrict__ Cout, float* __restrict__ statraw) {
  constexpr int BUF = 41 * 1024;
  __shared__ __align__(16) char lds[2 * BUF];
  int bz = blockIdx.x & 7;
  int inner = blockIdx.x >> 3;
  int t0 = (inner & 3) * 256;
  int og = inner >> 2;
  int o0 = og * 192;
  int wave = TID >> 6, lane = TID & 63;
  int l4 = lane >> 4, r15 = lane & 15;
  int wm = wave >> 2, wn = wave & 3;
  const __hip_bfloat16* hTb = hT + (size_t)bz * 1056 * 512;

  f32x4 acc[3][4];
  f32x4 zz = {0.f, 0.f, 0.f, 0.f};
  #pragma unroll
  for (int m = 0; m < 3; ++m)
    #pragma unroll
    for (int n = 0; n < 4; ++n) acc[m][n] = zz;

  auto stage = [&](int kt, int buf) {
    char* dst = lds + buf * BUF;
    #pragma unroll
    for (int c = 0; c < 3; ++c) {
      int ch = c * 16 + wave;
      if (ch < 41) {
        const __hip_bfloat16* src;
        if (ch < 24) {
          int j = (ch >= 12) ? 1 : 0;
          int rg = ch - j * 12;
          src = A1s + ((size_t)j * 1536 + o0 + rg * 16 + r15) * 512 + kt * 32 + l4 * 8;
        } else {
          int rg = ch - 24;   // window rows 16+t0 .. 16+t0+271
          src = hTb + (size_t)(16 + t0 + rg * 16 + r15) * 512 + kt * 32 + l4 * 8;
        }
        async16(src, dst + ch * 1024 + lane * 16);
      }
    }
  };

  stage(0, 0);
  __syncthreads();
  for (int kt = 0; kt < 16; ++kt) {
    if (kt + 1 < 16) stage(kt + 1, (kt + 1) & 1);
    char* cur = lds + (kt & 1) * BUF;
    #pragma unroll
    for (int j = 0; j < 2; ++j) {
      bf16x8 af[3], bfr[4];
      #pragma unroll
      for (int m = 0; m < 3; ++m)
        af[m] = *reinterpret_cast<const bf16x8*>(cur + (j * 12 + wm * 3 + m) * 1024 + lane * 16);
      #pragma unroll
      for (int n = 0; n < 4; ++n) {
        int q = (wn * 4 + n) * 16 + r15 + j;   // window row offset for output col + tap
        bfr[n] = *reinterpret_cast<const bf16x8*>(cur + 24 * 1024 + (q >> 4) * 1024 + l4 * 256 + (q & 15) * 16);
      }
      #pragma unroll
      for (int m = 0; m < 3; ++m)
        #pragma unroll
        for (int n = 0; n < 4; ++n)
          acc[m][n] = __builtin_amdgcn_mfma_f32_16x16x32_bf16(af[m], bfr[n], acc[m][n], 0, 0, 0);
    }
    __syncthreads();
  }

  // epilogue: bf16 store (+bias); block covers exactly one GN group (192 rows)
  float* sred = reinterpret_cast<float*>(lds);
  #pragma unroll
  for (int m = 0; m < 3; ++m) {
    float s = 0.f, ss2 = 0.f;
    #pragma unroll
    for (int n = 0; n < 4; ++n) {
      int ocol = t0 + (wn * 4 + n) * 16 + r15;
      #pragma unroll
      for (int r = 0; r < 4; ++r) {
        int orow = o0 + (wm * 3 + m) * 16 + l4 * 4 + r;
        float v = acc[m][n][r] + bias[orow];
        Cout[((size_t)bz * C3 + orow) * 1024 + ocol] = __float2bfloat16(v);
        s += v;
        ss2 += v * v;
      }
    }
    #pragma unroll
    for (int off = 1; off < 64; off <<= 1) {
      s   += __shfl_xor(s, off);
      ss2 += __shfl_xor(ss2, off);
    }
    if (lane == 0) {
      sred[(wave * 3 + m) * 2]     = s;
      sred[(wave * 3 + m) * 2 + 1] = ss2;
    }
  }
  __syncthreads();
  if (TID == 0) {
    float S = 0.f, SS = 0.f;
    #pragma unroll
    for (int slot = 0; slot < 48; ++slot) {
      S  += sred[slot * 2];
      SS += sred[slot * 2 + 1];
    }
    int g = bz * 8 + og;
    atomicAdd(&statraw[2 * g],     S);
    atomicAdd(&statraw[2 * g + 1], SS);
  }
}

// ---------------- shift-conv GEMM (conv K=4), batch-per-XCD affinity grid (R18-proven) --------
__global__ __launch_bounds__(256) void gemm_c4b(const __hip_bfloat16* __restrict__ A2,
    const __hip_bfloat16* __restrict__ aT, const float* __restrict__ bias,
    float* __restrict__ Cout, float* __restrict__ statraw) {
  constexpr int BUF = 42 * 1024;
  __shared__ __align__(16) char lds[2 * BUF];
  int bz = blockIdx.x & 7;
  int inner = blockIdx.x >> 3;
  int t0 = (inner & 7) * 128;
  int o0 = (inner >> 3) * 128;
  int wave = TID >> 6, lane = TID & 63;
  int l4 = lane >> 4, r15 = lane & 15;
  int wm = wave >> 1, wn = wave & 1;
  const __hip_bfloat16* aTb = aT + (size_t)bz * 1056 * 512;

  f32x4 acc[4][4];
  f32x4 zz = {0.f, 0.f, 0.f, 0.f};
  #pragma unroll
  for (int m = 0; m < 4; ++m)
    #pragma unroll
    for (int n = 0; n < 4; ++n) acc[m][n] = zz;

  auto stage = [&](int kt, int buf) {
    char* dst = lds + buf * BUF;
    #pragma unroll
    for (int c = 0; c < 11; ++c) {
      int ch = c * 4 + wave;
      if (ch < 42) {
        const __hip_bfloat16* src;
        if (ch < 32) {
          int j = ch >> 3, rg = ch & 7;
          src = A2 + ((size_t)j * 512 + o0 + rg * 16 + r15) * 512 + kt * 32 + l4 * 8;
        } else {
          int rg = ch - 32;
          src = aTb + (size_t)(t0 + rg * 16 + r15) * 512 + kt * 32 + l4 * 8;
        }
        async16(src, dst + ch * 1024 + lane * 16);
      }
    }
  };

  stage(0, 0);
  __syncthreads();
  for (int kt = 0; kt < 16; ++kt) {
    if (kt + 1 < 16) stage(kt + 1, (kt + 1) & 1);
    char* cur = lds + (kt & 1) * BUF;
    #pragma unroll
    for (int j = 0; j < 4; ++j) {
      bf16x8 af[4], bfr[4];
      #pragma unroll
      for (int m = 0; m < 4; ++m)
        af[m] = *reinterpret_cast<const bf16x8*>(cur + (j * 8 + wm * 4 + m) * 1024 + lane * 16);
      #pragma unroll
      for (int n = 0; n < 4; ++n) {
        int q = (wn * 4 + n) * 16 + r15 + j + 15;
        bfr[n] = *reinterpret_cast<const bf16x8*>(cur + 32 * 1024 + (q >> 4) * 1024 + l4 * 256 + (q & 15) * 16);
      }
      #pragma unroll
      for (int m = 0; m < 4; ++m)
        #pragma unroll
        for (int n = 0; n < 4; ++n)
          acc[m][n] = __builtin_amdgcn_mfma_f32_16x16x32_bf16(af[m], bfr[n], acc[m][n], 0, 0, 0);
    }
    __syncthreads();
  }

  float* sred = reinterpret_cast<float*>(lds);
  #pragma unroll
  for (int m = 0; m < 4; ++m) {
    float s = 0.f, ss2 = 0.f;
    #pragma unroll
    for (int n = 0; n < 4; ++n) {
      int ocol = t0 + (wn * 4 + n) * 16 + r15;
      #pragma unroll
      for (int r = 0; r < 4; ++r) {
        int orow = o0 + (wm * 4 + m) * 16 + l4 * 4 + r;
        float v = acc[m][n][r] + bias[orow];
        Cout[((size_t)bz * Cc + orow) * 1024 + ocol] = v;
        s += v;
        ss2 += v * v;
      }
    }
    #pragma unroll
    for (int off = 1; off < 64; off <<= 1) {
      s   += __shfl_xor(s, off);
      ss2 += __shfl_xor(ss2, off);
    }
    if (lane == 0) {
      sred[(wave * 4 + m) * 2]     = s;
      sred[(wave * 4 + m) * 2 + 1] = ss2;
    }
  }
  __syncthreads();
  if (TID < 2) {
    int g0 = o0 >> 6;
    float S = 0.f, SS = 0.f;
    int cnt = 0;
    #pragma unroll
    for (int slot = 0; slot < 16; ++slot) {
      int rc = ((slot >> 3) << 2) + (slot & 3);
      int g = (o0 + rc * 16) >> 6;
      if (g == g0 + (int)TID) {
        S  += sred[slot * 2];
        SS += sred[slot * 2 + 1];
        ++cnt;
      }
    }
    if (cnt) {
      atomicAdd(&statraw[2 * (bz * 8 + g0 + TID)],     S);
      atomicAdd(&statraw[2 * (bz * 8 + g0 + TID) + 1], SS);
    }
  }
}

// ---------------- fused GN(8)+Mish + build attn input images (bf16 qkv input, raw stats) ----------------
__global__ __launch_bounds__(256) void gn2_prep(const __hip_bfloat16* __restrict__ qkv,
    const float* __restrict__ straw, const float* __restrict__ w, const float* __restrict__ bv,
    char* __restrict__ qTp, char* __restrict__ kimg, char* __restrict__ vimg) {
  __shared__ unsigned short hbf[192 * 66];
  int tl = blockIdx.x & 15, hb = blockIdx.x >> 4;
  int b = hb >> 3, hd = hb & 7;
  float rs = straw[2 * (b * 8 + hd)], rq = straw[2 * (b * 8 + hd) + 1];
  float mean = rs * (1.f / 196608.f);
  float rstd = rsqrtf(fmaxf(rq * (1.f / 196608.f) - mean * mean, 0.f) + 1e-5f);
  for (int task = TID; task < 768; task += 256) {
    int row = task >> 2, seg = task & 3;
    int ch = hd * 192 + row;
    float sw = w[ch] * rstd;
    float sb = bv[ch] - mean * sw;
    const uint4* src = reinterpret_cast<const uint4*>(
        qkv + ((size_t)(b * C3 + ch)) * 1024 + tl * 64 + seg * 16);
    uint4 u0 = src[0], u1 = src[1];
    unsigned int uu[8] = {u0.x, u0.y, u0.z, u0.w, u1.x, u1.y, u1.z, u1.w};
    unsigned int* dst = reinterpret_cast<unsigned int*>(&hbf[row * 66 + seg * 16]);
    #pragma unroll
    for (int j = 0; j < 8; ++j) {
      float a = mishf(bf2f((unsigned short)(uu[j] & 0xffff)) * sw + sb);
      float c = mishf(bf2f((unsigned short)(uu[j] >> 16)) * sw + sb);
      dst[j] = pack2bf(a, c);
    }
  }
  __syncthreads();
  size_t tileof = ((size_t)hb * 16 + tl) * 8192;
  {
    int t = TID & 63, sel = TID >> 6;
    int img = sel >> 1, half = sel & 1;
    char* obase = (img == 0 ? qTp : kimg) + tileof + (size_t)t * 128;
    #pragma unroll
    for (int cc = 0; cc < 4; ++cc) {
      int chunk = half * 4 + cc;
      uint4 u;
      unsigned int* up = reinterpret_cast<unsigned int*>(&u);
      #pragma unroll
      for (int j = 0; j < 4; ++j) {
        int c = chunk * 8 + j * 2;
        unsigned int lo = hbf[(img * 64 + c) * 66 + t];
        unsigned int hi = hbf[(img * 64 + c + 1) * 66 + t];
        up[j] = lo | (hi << 16);
      }
      int cpos = (img == 0) ? chunk : (chunk ^ (t & 7));
      *reinterpret_cast<uint4*>(obase + cpos * 16) = u;
    }
  }
  {
    int c = TID & 63, qtr = TID >> 6;
    const unsigned int* vrow = reinterpret_cast<const unsigned int*>(&hbf[(128 + c) * 66]);
    char* obase = vimg + tileof + (size_t)c * 128;
    #pragma unroll
    for (int k = 0; k < 2; ++k) {
      int chunk = qtr * 2 + k;
      uint4 u;
      unsigned int* up = reinterpret_cast<unsigned int*>(&u);
      #pragma unroll
      for (int j = 0; j < 4; ++j) up[j] = vrow[chunk * 4 + j];
      *reinterpret_cast<uint4*>(obase + (chunk ^ (c & 7)) * 16) = u;
    }
  }
}

// ---------------- MFMA flash attention v6: KVBLK=128 (R17-proven) ----------------
__global__ __launch_bounds__(1024) void attn_mfma6(const char* __restrict__ qTp,
    const char* __restrict__ kimg, const char* __restrict__ vimg,
    __hip_bfloat16* __restrict__ aT) {
  __shared__ __align__(16) char smem[131072];
  char* kbuf0 = smem;
  char* kbuf1 = smem + 16384;
  char* vbuf0 = smem + 32768;
  char* vbuf1 = smem + 49152;
  char* pp    = smem + 65536;  // 16 waves x 4KB
  char* ov    = smem;          // 32KB alias (dead K/V buffers)

  int hb = blockIdx.y;
  int b = hb >> 3, hd = hb & 7;
  int lane = TID & 63, wave = TID >> 6;
  int qt = wave >> 2, qw = wave & 3;
  int l4 = lane >> 4, r15 = lane & 15;
  size_t ibase = (size_t)hb * 16 * 8192;
  const char* ksrc = kimg + ibase;
  const char* vsrc = vimg + ibase;

  async16(ksrc + (size_t)TID * 16, kbuf0 + (size_t)TID * 16);
  async16(vsrc + (size_t)TID * 16, vbuf0 + (size_t)TID * 16);

  bf16x8 aq[2];
  int tg = qw * 16 + r15;
  const char* qrow = qTp + ibase + (size_t)(blockIdx.x * 4 + qt) * 8192 + (size_t)tg * 128;
  aq[0] = *reinterpret_cast<const bf16x8*>(qrow + l4 * 16);
  aq[1] = *reinterpret_cast<const bf16x8*>(qrow + 64 + l4 * 16);
  {
    const float SC = 0.125f * 1.44269504f;
    #pragma unroll
    for (int kk = 0; kk < 2; ++kk) {
      unsigned int* u = reinterpret_cast<unsigned int*>(&aq[kk]);
      #pragma unroll
      for (int j = 0; j < 4; ++j) {
        float lo = bf2f((unsigned short)(u[j] & 0xffff)) * SC;
        float hi = bf2f((unsigned short)(u[j] >> 16)) * SC;
        u[j] = pack2bf(lo, hi);
      }
    }
  }

  f32x4 osum[4];
  f32x4 zz = {0.f, 0.f, 0.f, 0.f};
  #pragma unroll
  for (int cf = 0; cf < 4; ++cf) osum[cf] = zz;
  float mrow[4] = {-1e30f, -1e30f, -1e30f, -1e30f};
  float lrow[4] = {0.f, 0.f, 0.f, 0.f};
  __syncthreads();

  for (int it = 0; it < 8; ++it) {
    char* kcur = (it & 1) ? kbuf1 : kbuf0;
    char* vcur = (it & 1) ? vbuf1 : vbuf0;
    if (it < 7) {
      char* knxt = (it & 1) ? kbuf0 : kbuf1;
      char* vnxt = (it & 1) ? vbuf0 : vbuf1;
      const char* kn = ksrc + (size_t)(it + 1) * 16384;
      const char* vn = vsrc + (size_t)(it + 1) * 16384;
      async16(kn + (size_t)TID * 16, knxt + (size_t)TID * 16);
      async16(vn + (size_t)TID * 16, vnxt + (size_t)TID * 16);
    }
    f32x4 sc[8];
    #pragma unroll
    for (int sf = 0; sf < 8; ++sf) sc[sf] = zz;
    #pragma unroll
    for (int sf = 0; sf < 8; ++sf) {
      int sr = sf * 16 + r15;
      #pragma unroll
      for (int kk = 0; kk < 2; ++kk) {
        bf16x8 bk = *reinterpret_cast<const bf16x8*>(kcur + sr * 128 + (((kk * 4 + l4) ^ (sr & 7)) << 4));
        sc[sf] = __builtin_amdgcn_mfma_f32_16x16x32_bf16(aq[kk], bk, sc[sf], 0, 0, 0);
      }
    }
    float tmax[4];
    #pragma unroll
    for (int r = 0; r < 4; ++r) {
      float m0 = fmaxf(fmaxf(sc[0][r], sc[1][r]), fmaxf(sc[2][r], sc[3][r]));
      float m1 = fmaxf(fmaxf(sc[4][r], sc[5][r]), fmaxf(sc[6][r], sc[7][r]));
      tmax[r] = fmaxf(m0, m1);
    }
    #pragma unroll
    for (int off = 1; off < 16; off <<= 1)
      #pragma unroll
      for (int r = 0; r < 4; ++r) tmax[r] = fmaxf(tmax[r], __shfl_xor(tmax[r], off));
    bool grow = (tmax[0] > mrow[0]) | (tmax[1] > mrow[1]) |
                (tmax[2] > mrow[2]) | (tmax[3] > mrow[3]);
    if (grow) {
      float alpha[4];
      #pragma unroll
      for (int r = 0; r < 4; ++r) {
        float mnew = fmaxf(mrow[r], tmax[r]);
        alpha[r] = exp2_hw(mrow[r] - mnew);
        mrow[r] = mnew;
        lrow[r] *= alpha[r];
      }
      #pragma unroll
      for (int cf = 0; cf < 4; ++cf)
        #pragma unroll
        for (int r = 0; r < 4; ++r) osum[cf][r] *= alpha[r];
    }
    char* pw = pp + wave * 4096;
    float psum[4] = {0.f, 0.f, 0.f, 0.f};
    #pragma unroll
    for (int sf = 0; sf < 8; ++sf) {
      int s = sf * 16 + r15;
      int chunk = s >> 3;
      #pragma unroll
      for (int r = 0; r < 4; ++r) {
        float p = exp2_hw(sc[sf][r] - mrow[r]);
        psum[r] += p;
        int tlc = l4 * 4 + r;
        *reinterpret_cast<__hip_bfloat16*>(pw + tlc * 256 + (((chunk ^ (tlc & 15)) << 4) | ((s & 7) * 2)))
            = __float2bfloat16(p);
      }
    }
    #pragma unroll
    for (int r = 0; r < 4; ++r) lrow[r] += psum[r];
    asm volatile("s_waitcnt lgkmcnt(0)" ::: "memory");
    __builtin_amdgcn_sched_barrier(0);

    bf16x8 pa[4];
    #pragma unroll
    for (int kk2 = 0; kk2 < 4; ++kk2)
      pa[kk2] = *reinterpret_cast<const bf16x8*>(pw + r15 * 256 + (((kk2 * 4 + l4) ^ (r15 & 15)) << 4));
    #pragma unroll
    for (int cf = 0; cf < 4; ++cf) {
      int cr = cf * 16 + r15;
      #pragma unroll
      for (int kk2 = 0; kk2 < 4; ++kk2) {
        bf16x8 bv = *reinterpret_cast<const bf16x8*>(vcur + (kk2 >> 1) * 8192 + cr * 128 +
                                                     ((((kk2 & 1) * 4 + l4) ^ (cr & 7)) << 4));
        osum[cf] = __builtin_amdgcn_mfma_f32_16x16x32_bf16(pa[kk2], bv, osum[cf], 0, 0, 0);
      }
    }
    __syncthreads();
  }

  #pragma unroll
  for (int off = 1; off < 16; off <<= 1)
    #pragma unroll
    for (int r = 0; r < 4; ++r) lrow[r] += __shfl_xor(lrow[r], off);
  float linv[4];
  #pragma unroll
  for (int r = 0; r < 4; ++r) linv[r] = 1.f / lrow[r];

  #pragma unroll
  for (int cf = 0; cf < 4; ++cf) {
    int c = cf * 16 + r15;
    #pragma unroll
    for (int r = 0; r < 4; ++r) {
      int t = qt * 64 + qw * 16 + l4 * 4 + r;
      *reinterpret_cast<__hip_bfloat16*>(ov + t * 128 + ((((c >> 3) ^ (t & 7)) << 4) | ((c & 7) * 2)))
          = __float2bfloat16(osum[cf][r] * linv[r]);
    }
  }
  __syncthreads();
  __hip_bfloat16* ap = aT + ((size_t)b * 1056 + 16 + blockIdx.x * 256) * 512 + hd * 64;
  for (int u = TID; u < 2048; u += 1024) {
    int t = u >> 3, cj = u & 7;
    uint4 o4 = *reinterpret_cast<const uint4*>(ov + t * 128 + ((cj ^ (t & 7)) << 4));
    *reinterpret_cast<uint4*>(ap + (size_t)t * 512 + cj * 8) = o4;
  }
}

// ---------------- final: out = x + mish(gn(y2)) in-place on d_out (raw stats) ----------------
__global__ __launch_bounds__(256) void final_kernel(const float* __restrict__ x,
    float* __restrict__ y, const float* __restrict__ straw,
    const float* __restrict__ w, const float* __restrict__ bv) {
  size_t i = ((size_t)blockIdx.x * 256 + TID) * 4;
  int ch = (int)((i >> 10) & (Cc - 1));
  int b = (int)(i >> 19);
  int g = b * 8 + (ch >> 6);
  float rs = straw[2 * g], rq = straw[2 * g + 1];
  float mean = rs * (1.f / 65536.f);
  float rstd = rsqrtf(fmaxf(rq * (1.f / 65536.f) - mean * mean, 0.f) + 1e-5f);
  float sw = w[ch] * rstd;
  float sb = bv[ch] - mean * sw;
  float4 v  = *reinterpret_cast<const float4*>(y + i);
  float4 xv = *reinterpret_cast<const float4*>(x + i);
  v.x = xv.x + mishf(v.x * sw + sb);
  v.y = xv.y + mishf(v.y * sw + sb);
  v.z = xv.z + mishf(v.z * sw + sb);
  v.w = xv.w + mishf(v.w * sw + sb);
  *reinterpret_cast<float4*>(y + i) = v;
}

extern "C" void kernel_launch(void* const* d_in, const int* in_sizes, int n_in,
                              void* d_out, int out_size, void* d_ws, size_t ws_size,
                              hipStream_t stream) {
  const float* x     = (const float*)d_in[0];
  const float* gn_w  = (const float*)d_in[1];
  const float* gn_b  = (const float*)d_in[2];
  const float* wqkv  = (const float*)d_in[3];
  const float* bqkv  = (const float*)d_in[4];
  const float* gnq_w = (const float*)d_in[5];
  const float* gnq_b = (const float*)d_in[6];
  const float* wproj = (const float*)d_in[7];
  const float* bproj = (const float*)d_in[8];
  const float* gnp_w = (const float*)d_in[9];
  const float* gnp_b = (const float*)d_in[10];
  float* out = (float*)d_out;

  char* ws = (char*)d_ws;
  const size_t MB = 1024 * 1024;
  // Time-multiplexed workspace:
  __hip_bfloat16* qkvb = (__hip_bfloat16*)ws;            // [0,24MB)   step6 -> step7
  __hip_bfloat16* aT   = (__hip_bfloat16*)(ws + 24 * MB);// [24,33MB)  step2/8 -> step10 (padded)
  __hip_bfloat16* A1s  = (__hip_bfloat16*)(ws + 40 * MB);// [40,43MB)  step4 -> step6
  __hip_bfloat16* A2   = (__hip_bfloat16*)(ws + 44 * MB);// [44,46MB)  step9 -> step10
  char* vimg = ws + 56 * MB;                             // [56,64MB)  step7 -> step8
  float* st2raw = (float*)(ws + 64 * MB);
  float* st3raw = st2raw + 128;
  __hip_bfloat16* hT = (__hip_bfloat16*)d_out;           // d_out[0,8.44MB) step3/5 -> step6 (padded; dead before step7 writes)
  char* qTp  = (char*)d_out;                             // d_out[0,8MB)  step7 -> step8
  char* kimg = (char*)d_out + 8 * MB;                    // d_out[8,16MB) step7 -> step8

  dim3 blk(256);
  zero_stats<<<1, blk, 0, stream>>>(st2raw);                                        // 1
  zero_pads<<<64, blk, 0, stream>>>(aT);                                            // 2
  zero_pads<<<64, blk, 0, stream>>>(hT);                                            // 3
  cast_wqkv<<<1536, blk, 0, stream>>>(wqkv, A1s);                                   // 4
  gn1_hT<<<256, blk, 0, stream>>>(x, gn_w, gn_b, hT);                               // 5
  gemm_s2<<<256, dim3(1024), 0, stream>>>(A1s, hT, bqkv, qkvb, st2raw);             // 6
  gn2_prep<<<1024, blk, 0, stream>>>(qkvb, st2raw, gnq_w, gnq_b, qTp, kimg, vimg);  // 7
  attn_mfma6<<<dim3(4, 64), dim3(1024), 0, stream>>>(qTp, kimg, vimg, aT);          // 8
  cast_wproj<<<512, blk, 0, stream>>>(wproj, A2);                                   // 9
  gemm_c4b<<<256, blk, 0, stream>>>(A2, aT, bproj, out, st3raw);                    // 10
  final_kernel<<<4096, blk, 0, stream>>>(x, out, st3raw, gnp_w, gnp_b);             // 11
}

// Round 22
// 144.031 us; speedup vs baseline: 1.3819x; 1.0795x over previous
//
#include <hip/hip_runtime.h>
#include <hip/hip_bf16.h>
#include <math.h>

#define TID threadIdx.x

constexpr int Cc = 512, Tt = 1024, C3 = 1536;

typedef __attribute__((ext_vector_type(8))) __bf16 bf16x8;
typedef __attribute__((ext_vector_type(4))) float f32x4;

__device__ __forceinline__ void async16(const void* g, void* l) {
  __builtin_amdgcn_global_load_lds(
      (const __attribute__((address_space(1))) unsigned int*)g,
      (__attribute__((address_space(3))) unsigned int*)l, 16, 0, 0);
}

__device__ __forceinline__ unsigned int pack2bf(float a, float b) {
  __hip_bfloat162 h;
  h.x = __float2bfloat16(a);
  h.y = __float2bfloat16(b);
  return *reinterpret_cast<unsigned int*>(&h);
}

__device__ __forceinline__ float bf2f(unsigned short u) {
  unsigned int t = ((unsigned int)u) << 16;
  union { unsigned int i; float f; } c;
  c.i = t;
  return c.f;
}

// hardware 2^x (v_exp_f32: D = 2^S0)
__device__ __forceinline__ float exp2_hw(float x) {
  float r;
  asm("v_exp_f32 %0, %1" : "=v"(r) : "v"(x));
  return r;
}

// mish(x) = x * n/(n+2), n = u*(u+2), u = e^x  (one hw exp + one rcp)
__device__ __forceinline__ float mishf(float x) {
  float u = __expf(x);
  float n = u * (u + 2.f);
  float r = x * n * __builtin_amdgcn_rcpf(n + 2.f);
  return (x > 20.f) ? x : r;
}

__device__ __forceinline__ void blockReduce2(float& s, float& ss) {
  #pragma unroll
  for (int off = 32; off > 0; off >>= 1) {
    s  += __shfl_xor(s,  off);
    ss += __shfl_xor(ss, off);
  }
  __shared__ float ls[4], lss[4];
  int w = TID >> 6;
  if ((TID & 63) == 0) { ls[w] = s; lss[w] = ss; }
  __syncthreads();
  s  = ls[0] + ls[1] + ls[2] + ls[3];
  ss = lss[0] + lss[1] + lss[2] + lss[3];
}

// ---------------- fused misc prep: zero pads (aT,hT) + weight casts + zero stats ----------------
// blocks [0,64): aT pads | [64,128): hT pads | [128,1664): cast_wqkv | [1664,2176): cast_wproj
// | 2176: zero stats(256 floats)
__global__ __launch_bounds__(256) void prep_misc(const float* __restrict__ wq,
    const float* __restrict__ wp, __hip_bfloat16* __restrict__ A1s,
    __hip_bfloat16* __restrict__ A2, __hip_bfloat16* __restrict__ aT,
    __hip_bfloat16* __restrict__ hT, float* __restrict__ stats) {
  int bid = blockIdx.x;
  if (bid < 128) {
    __hip_bfloat16* dst = (bid < 64) ? aT : hT;
    int idx = ((bid & 63)) * 256 + TID;
    int bb = idx >> 11;
    int task = idx & 2047;
    int prow = task >> 6;
    int col = (task & 63) * 8;
    int P = (prow < 16) ? prow : (1024 + prow);
    uint4 z = {0u, 0u, 0u, 0u};
    *reinterpret_cast<uint4*>(dst + ((size_t)bb * 1056 + P) * 512 + col) = z;
  } else if (bid < 1664) {
    int o = bid - 128;
    int ci = TID * 2;
    float4 v = *reinterpret_cast<const float4*>(wq + ((size_t)o * 512 + ci) * 2);
    unsigned int u0 = pack2bf(v.x, v.z);
    unsigned int u1 = pack2bf(v.y, v.w);
    *reinterpret_cast<unsigned int*>(A1s + (size_t)o * 512 + ci) = u0;
    *reinterpret_cast<unsigned int*>(A1s + ((size_t)1536 + o) * 512 + ci) = u1;
  } else if (bid < 2176) {
    int o = bid - 1664;
    int ci = TID * 2;
    float4 v0 = *reinterpret_cast<const float4*>(wp + ((size_t)o * 512 + ci) * 4);
    float4 v1 = *reinterpret_cast<const float4*>(wp + ((size_t)o * 512 + ci + 1) * 4);
    const float* a0 = &v0.x;
    const float* a1 = &v1.x;
    #pragma unroll
    for (int j = 0; j < 4; ++j) {
      unsigned int u = pack2bf(a0[j], a1[j]);
      *reinterpret_cast<unsigned int*>(A2 + ((size_t)j * 512 + o) * 512 + ci) = u;
    }
  } else {
    stats[TID] = 0.f;
  }
}

// ---------------- fused GN(32) -> bf16 hT[b][16+t][ci] (transposed, padded, NO im2col dup) ----
__global__ __launch_bounds__(256) void gn1_hT(const float* __restrict__ x,
    const float* __restrict__ w, const float* __restrict__ bv,
    __hip_bfloat16* __restrict__ hT) {
  __shared__ float hs[16][262];
  int blk = blockIdx.x, bb = blk >> 5, g = blk & 31;
  size_t base = ((size_t)bb * Cc + g * 16) * Tt;
  const float* xp = x + base;
  float s = 0.f, ss = 0.f;
  for (int i = TID * 4; i < 16 * Tt; i += 1024) {
    float4 v = *reinterpret_cast<const float4*>(xp + i);
    s  += v.x + v.y + v.z + v.w;
    ss += v.x * v.x + v.y * v.y + v.z * v.z + v.w * v.w;
  }
  blockReduce2(s, ss);
  float mean = s * (1.f / 16384.f);
  float rstd = rsqrtf(ss * (1.f / 16384.f) - mean * mean + 1e-5f);

  __hip_bfloat16* ob = hT + (size_t)bb * 1056 * 512 + g * 16;
  for (int tc = 0; tc < 4; ++tc) {
    int tbase = tc * 256;
    __syncthreads();
    for (int task = TID; task < 1024; task += 256) {
      int row = task >> 6, c4 = task & 63;
      int ch = g * 16 + row;
      float sw = w[ch] * rstd;
      float sb = bv[ch] - mean * sw;
      float4 v = *reinterpret_cast<const float4*>(xp + (size_t)row * Tt + tbase + c4 * 4);
      hs[row][c4 * 4 + 0] = v.x * sw + sb;
      hs[row][c4 * 4 + 1] = v.y * sw + sb;
      hs[row][c4 * 4 + 2] = v.z * sw + sb;
      hs[row][c4 * 4 + 3] = v.w * sw + sb;
    }
    __syncthreads();
    for (int task = TID; task < 512; task += 256) {
      int t = task >> 1, half = task & 1;
      int c0 = half * 8;
      uint4 u;
      u.x = pack2bf(hs[c0 + 0][t], hs[c0 + 1][t]);
      u.y = pack2bf(hs[c0 + 2][t], hs[c0 + 3][t]);
      u.z = pack2bf(hs[c0 + 4][t], hs[c0 + 5][t]);
      u.w = pack2bf(hs[c0 + 6][t], hs[c0 + 7][t]);
      *reinterpret_cast<uint4*>(ob + (size_t)(16 + tbase + t) * 512 + c0) = u;
    }
  }
}

// ---------------- shift-conv GEMM for conv K=2 (gemm1): BM=192 x BN=256, 1024 thr (R21-proven) --
__global__ __launch_bounds__(1024, 4) void gemm_s2(const __hip_bfloat16* __restrict__ A1s,
    const __hip_bfloat16* __restrict__ hT, const float* __restrict__ bias,
    __hip_bfloat16* __restrict__ Cout, float* __restrict__ statraw) {
  constexpr int BUF = 41 * 1024;
  __shared__ __align__(16) char lds[2 * BUF];
  int bz = blockIdx.x & 7;
  int inner = blockIdx.x >> 3;
  int t0 = (inner & 3) * 256;
  int og = inner >> 2;
  int o0 = og * 192;
  int wave = TID >> 6, lane = TID & 63;
  int l4 = lane >> 4, r15 = lane & 15;
  int wm = wave >> 2, wn = wave & 3;
  const __hip_bfloat16* hTb = hT + (size_t)bz * 1056 * 512;

  f32x4 acc[3][4];
  f32x4 zz = {0.f, 0.f, 0.f, 0.f};
  #pragma unroll
  for (int m = 0; m < 3; ++m)
    #pragma unroll
    for (int n = 0; n < 4; ++n) acc[m][n] = zz;

  auto stage = [&](int kt, int buf) {
    char* dst = lds + buf * BUF;
    #pragma unroll
    for (int c = 0; c < 3; ++c) {
      int ch = c * 16 + wave;
      if (ch < 41) {
        const __hip_bfloat16* src;
        if (ch < 24) {
          int j = (ch >= 12) ? 1 : 0;
          int rg = ch - j * 12;
          src = A1s + ((size_t)j * 1536 + o0 + rg * 16 + r15) * 512 + kt * 32 + l4 * 8;
        } else {
          int rg = ch - 24;
          src = hTb + (size_t)(16 + t0 + rg * 16 + r15) * 512 + kt * 32 + l4 * 8;
        }
        async16(src, dst + ch * 1024 + lane * 16);
      }
    }
  };

  stage(0, 0);
  __syncthreads();
  for (int kt = 0; kt < 16; ++kt) {
    if (kt + 1 < 16) stage(kt + 1, (kt + 1) & 1);
    char* cur = lds + (kt & 1) * BUF;
    #pragma unroll
    for (int j = 0; j < 2; ++j) {
      bf16x8 af[3], bfr[4];
      #pragma unroll
      for (int m = 0; m < 3; ++m)
        af[m] = *reinterpret_cast<const bf16x8*>(cur + (j * 12 + wm * 3 + m) * 1024 + lane * 16);
      #pragma unroll
      for (int n = 0; n < 4; ++n) {
        int q = (wn * 4 + n) * 16 + r15 + j;
        bfr[n] = *reinterpret_cast<const bf16x8*>(cur + 24 * 1024 + (q >> 4) * 1024 + l4 * 256 + (q & 15) * 16);
      }
      #pragma unroll
      for (int m = 0; m < 3; ++m)
        #pragma unroll
        for (int n = 0; n < 4; ++n)
          acc[m][n] = __builtin_amdgcn_mfma_f32_16x16x32_bf16(af[m], bfr[n], acc[m][n], 0, 0, 0);
    }
    __syncthreads();
  }

  float* sred = reinterpret_cast<float*>(lds);
  #pragma unroll
  for (int m = 0; m < 3; ++m) {
    float s = 0.f, ss2 = 0.f;
    #pragma unroll
    for (int n = 0; n < 4; ++n) {
      int ocol = t0 + (wn * 4 + n) * 16 + r15;
      #pragma unroll
      for (int r = 0; r < 4; ++r) {
        int orow = o0 + (wm * 3 + m) * 16 + l4 * 4 + r;
        float v = acc[m][n][r] + bias[orow];
        Cout[((size_t)bz * C3 + orow) * 1024 + ocol] = __float2bfloat16(v);
        s += v;
        ss2 += v * v;
      }
    }
    #pragma unroll
    for (int off = 1; off < 64; off <<= 1) {
      s   += __shfl_xor(s, off);
      ss2 += __shfl_xor(ss2, off);
    }
    if (lane == 0) {
      sred[(wave * 3 + m) * 2]     = s;
      sred[(wave * 3 + m) * 2 + 1] = ss2;
    }
  }
  __syncthreads();
  if (TID == 0) {
    float S = 0.f, SS = 0.f;
    #pragma unroll
    for (int slot = 0; slot < 48; ++slot) {
      S  += sred[slot * 2];
      SS += sred[slot * 2 + 1];
    }
    int g = bz * 8 + og;
    atomicAdd(&statraw[2 * g],     S);
    atomicAdd(&statraw[2 * g + 1], SS);
  }
}

// ---------------- shift-conv GEMM (conv K=4) v2: BM=64 x BN=256, 256 thr (fewer A re-reads) ----
// y[b][o][t] = sum_j sum_ci A2[j][o][ci] * aT[b][16+t+j-1][ci] + bias[o]
// LDS/step: 16 A-chunks (4 planes x 4 rowgrp) + 18 B-chunks (288-row window) = 34KB; dbuf 68KB.
__global__ __launch_bounds__(256) void gemm_c4d(const __hip_bfloat16* __restrict__ A2,
    const __hip_bfloat16* __restrict__ aT, const float* __restrict__ bias,
    float* __restrict__ Cout, float* __restrict__ statraw) {
  constexpr int BUF = 34 * 1024;
  __shared__ __align__(16) char lds[2 * BUF];
  int bz = blockIdx.x & 7;
  int inner = blockIdx.x >> 3;
  int t0 = (inner & 3) * 256;
  int o0 = (inner >> 2) * 64;
  int wave = TID >> 6, lane = TID & 63;
  int l4 = lane >> 4, r15 = lane & 15;
  const __hip_bfloat16* aTb = aT + (size_t)bz * 1056 * 512;

  f32x4 acc[4][4];
  f32x4 zz = {0.f, 0.f, 0.f, 0.f};
  #pragma unroll
  for (int m = 0; m < 4; ++m)
    #pragma unroll
    for (int n = 0; n < 4; ++n) acc[m][n] = zz;

  auto stage = [&](int kt, int buf) {
    char* dst = lds + buf * BUF;
    #pragma unroll
    for (int c = 0; c < 9; ++c) {
      int ch = c * 4 + wave;
      if (ch < 34) {
        const __hip_bfloat16* src;
        if (ch < 16) {
          int j = ch >> 2, rg = ch & 3;
          src = A2 + ((size_t)j * 512 + o0 + rg * 16 + r15) * 512 + kt * 32 + l4 * 8;
        } else {
          int rg = ch - 16;   // window rows t0 .. t0+287 of padded aT
          src = aTb + (size_t)(t0 + rg * 16 + r15) * 512 + kt * 32 + l4 * 8;
        }
        async16(src, dst + ch * 1024 + lane * 16);
      }
    }
  };

  stage(0, 0);
  __syncthreads();
  for (int kt = 0; kt < 16; ++kt) {
    if (kt + 1 < 16) stage(kt + 1, (kt + 1) & 1);
    char* cur = lds + (kt & 1) * BUF;
    #pragma unroll
    for (int j = 0; j < 4; ++j) {
      bf16x8 af[4], bfr[4];
      #pragma unroll
      for (int m = 0; m < 4; ++m)
        af[m] = *reinterpret_cast<const bf16x8*>(cur + (j * 4 + m) * 1024 + lane * 16);
      #pragma unroll
      for (int n = 0; n < 4; ++n) {
        int q = (wave * 4 + n) * 16 + r15 + j + 15;  // aT row offset from t0 (pad 16, tap j-1)
        bfr[n] = *reinterpret_cast<const bf16x8*>(cur + 16 * 1024 + (q >> 4) * 1024 + l4 * 256 + (q & 15) * 16);
      }
      #pragma unroll
      for (int m = 0; m < 4; ++m)
        #pragma unroll
        for (int n = 0; n < 4; ++n)
          acc[m][n] = __builtin_amdgcn_mfma_f32_16x16x32_bf16(af[m], bfr[n], acc[m][n], 0, 0, 0);
    }
    __syncthreads();
  }

  // epilogue: f32 store + bias; block covers exactly one GN group (64 rows)
  float* sred = reinterpret_cast<float*>(lds);
  #pragma unroll
  for (int m = 0; m < 4; ++m) {
    float s = 0.f, ss2 = 0.f;
    #pragma unroll
    for (int n = 0; n < 4; ++n) {
      int ocol = t0 + (wave * 4 + n) * 16 + r15;
      #pragma unroll
      for (int r = 0; r < 4; ++r) {
        int orow = o0 + m * 16 + l4 * 4 + r;
        float v = acc[m][n][r] + bias[orow];
        Cout[((size_t)bz * Cc + orow) * 1024 + ocol] = v;
        s += v;
        ss2 += v * v;
      }
    }
    #pragma unroll
    for (int off = 1; off < 64; off <<= 1) {
      s   += __shfl_xor(s, off);
      ss2 += __shfl_xor(ss2, off);
    }
    if (lane == 0) {
      sred[(wave * 4 + m) * 2]     = s;
      sred[(wave * 4 + m) * 2 + 1] = ss2;
    }
  }
  __syncthreads();
  if (TID == 0) {
    float S = 0.f, SS = 0.f;
    #pragma unroll
    for (int slot = 0; slot < 16; ++slot) {
      S  += sred[slot * 2];
      SS += sred[slot * 2 + 1];
    }
    int g = bz * 8 + (o0 >> 6);
    atomicAdd(&statraw[2 * g],     S);
    atomicAdd(&statraw[2 * g + 1], SS);
  }
}

// ---------------- fused GN(8)+Mish + build attn input images (bf16 qkv input, raw stats) ----------------
__global__ __launch_bounds__(256) void gn2_prep(const __hip_bfloat16* __restrict__ qkv,
    const float* __restrict__ straw, const float* __restrict__ w, const float* __restrict__ bv,
    char* __restrict__ qTp, char* __restrict__ kimg, char* __restrict__ vimg) {
  __shared__ unsigned short hbf[192 * 66];
  int tl = blockIdx.x & 15, hb = blockIdx.x >> 4;
  int b = hb >> 3, hd = hb & 7;
  float rs = straw[2 * (b * 8 + hd)], rq = straw[2 * (b * 8 + hd) + 1];
  float mean = rs * (1.f / 196608.f);
  float rstd = rsqrtf(fmaxf(rq * (1.f / 196608.f) - mean * mean, 0.f) + 1e-5f);
  for (int task = TID; task < 768; task += 256) {
    int row = task >> 2, seg = task & 3;
    int ch = hd * 192 + row;
    float sw = w[ch] * rstd;
    float sb = bv[ch] - mean * sw;
    const uint4* src = reinterpret_cast<const uint4*>(
        qkv + ((size_t)(b * C3 + ch)) * 1024 + tl * 64 + seg * 16);
    uint4 u0 = src[0], u1 = src[1];
    unsigned int uu[8] = {u0.x, u0.y, u0.z, u0.w, u1.x, u1.y, u1.z, u1.w};
    unsigned int* dst = reinterpret_cast<unsigned int*>(&hbf[row * 66 + seg * 16]);
    #pragma unroll
    for (int j = 0; j < 8; ++j) {
      float a = mishf(bf2f((unsigned short)(uu[j] & 0xffff)) * sw + sb);
      float c = mishf(bf2f((unsigned short)(uu[j] >> 16)) * sw + sb);
      dst[j] = pack2bf(a, c);
    }
  }
  __syncthreads();
  size_t tileof = ((size_t)hb * 16 + tl) * 8192;
  {
    int t = TID & 63, sel = TID >> 6;
    int img = sel >> 1, half = sel & 1;
    char* obase = (img == 0 ? qTp : kimg) + tileof + (size_t)t * 128;
    #pragma unroll
    for (int cc = 0; cc < 4; ++cc) {
      int chunk = half * 4 + cc;
      uint4 u;
      unsigned int* up = reinterpret_cast<unsigned int*>(&u);
      #pragma unroll
      for (int j = 0; j < 4; ++j) {
        int c = chunk * 8 + j * 2;
        unsigned int lo = hbf[(img * 64 + c) * 66 + t];
        unsigned int hi = hbf[(img * 64 + c + 1) * 66 + t];
        up[j] = lo | (hi << 16);
      }
      int cpos = (img == 0) ? chunk : (chunk ^ (t & 7));
      *reinterpret_cast<uint4*>(obase + cpos * 16) = u;
    }
  }
  {
    int c = TID & 63, qtr = TID >> 6;
    const unsigned int* vrow = reinterpret_cast<const unsigned int*>(&hbf[(128 + c) * 66]);
    char* obase = vimg + tileof + (size_t)c * 128;
    #pragma unroll
    for (int k = 0; k < 2; ++k) {
      int chunk = qtr * 2 + k;
      uint4 u;
      unsigned int* up = reinterpret_cast<unsigned int*>(&u);
      #pragma unroll
      for (int j = 0; j < 4; ++j) up[j] = vrow[chunk * 4 + j];
      *reinterpret_cast<uint4*>(obase + (chunk ^ (c & 7)) * 16) = u;
    }
  }
}

// ---------------- MFMA flash attention v6: KVBLK=128 + T5 setprio on MFMA clusters ----------------
__global__ __launch_bounds__(1024) void attn_mfma6(const char* __restrict__ qTp,
    const char* __restrict__ kimg, const char* __restrict__ vimg,
    __hip_bfloat16* __restrict__ aT) {
  __shared__ __align__(16) char smem[131072];
  char* kbuf0 = smem;
  char* kbuf1 = smem + 16384;
  char* vbuf0 = smem + 32768;
  char* vbuf1 = smem + 49152;
  char* pp    = smem + 65536;  // 16 waves x 4KB
  char* ov    = smem;          // 32KB alias (dead K/V buffers)

  int hb = blockIdx.y;
  int b = hb >> 3, hd = hb & 7;
  int lane = TID & 63, wave = TID >> 6;
  int qt = wave >> 2, qw = wave & 3;
  int l4 = lane >> 4, r15 = lane & 15;
  size_t ibase = (size_t)hb * 16 * 8192;
  const char* ksrc = kimg + ibase;
  const char* vsrc = vimg + ibase;

  async16(ksrc + (size_t)TID * 16, kbuf0 + (size_t)TID * 16);
  async16(vsrc + (size_t)TID * 16, vbuf0 + (size_t)TID * 16);

  bf16x8 aq[2];
  int tg = qw * 16 + r15;
  const char* qrow = qTp + ibase + (size_t)(blockIdx.x * 4 + qt) * 8192 + (size_t)tg * 128;
  aq[0] = *reinterpret_cast<const bf16x8*>(qrow + l4 * 16);
  aq[1] = *reinterpret_cast<const bf16x8*>(qrow + 64 + l4 * 16);
  {
    const float SC = 0.125f * 1.44269504f;
    #pragma unroll
    for (int kk = 0; kk < 2; ++kk) {
      unsigned int* u = reinterpret_cast<unsigned int*>(&aq[kk]);
      #pragma unroll
      for (int j = 0; j < 4; ++j) {
        float lo = bf2f((unsigned short)(u[j] & 0xffff)) * SC;
        float hi = bf2f((unsigned short)(u[j] >> 16)) * SC;
        u[j] = pack2bf(lo, hi);
      }
    }
  }

  f32x4 osum[4];
  f32x4 zz = {0.f, 0.f, 0.f, 0.f};
  #pragma unroll
  for (int cf = 0; cf < 4; ++cf) osum[cf] = zz;
  float mrow[4] = {-1e30f, -1e30f, -1e30f, -1e30f};
  float lrow[4] = {0.f, 0.f, 0.f, 0.f};
  __syncthreads();

  for (int it = 0; it < 8; ++it) {
    char* kcur = (it & 1) ? kbuf1 : kbuf0;
    char* vcur = (it & 1) ? vbuf1 : vbuf0;
    if (it < 7) {
      char* knxt = (it & 1) ? kbuf0 : kbuf1;
      char* vnxt = (it & 1) ? vbuf0 : vbuf1;
      const char* kn = ksrc + (size_t)(it + 1) * 16384;
      const char* vn = vsrc + (size_t)(it + 1) * 16384;
      async16(kn + (size_t)TID * 16, knxt + (size_t)TID * 16);
      async16(vn + (size_t)TID * 16, vnxt + (size_t)TID * 16);
    }
    f32x4 sc[8];
    #pragma unroll
    for (int sf = 0; sf < 8; ++sf) sc[sf] = zz;
    __builtin_amdgcn_s_setprio(1);
    #pragma unroll
    for (int sf = 0; sf < 8; ++sf) {
      int sr = sf * 16 + r15;
      #pragma unroll
      for (int kk = 0; kk < 2; ++kk) {
        bf16x8 bk = *reinterpret_cast<const bf16x8*>(kcur + sr * 128 + (((kk * 4 + l4) ^ (sr & 7)) << 4));
        sc[sf] = __builtin_amdgcn_mfma_f32_16x16x32_bf16(aq[kk], bk, sc[sf], 0, 0, 0);
      }
    }
    __builtin_amdgcn_s_setprio(0);
    float tmax[4];
    #pragma unroll
    for (int r = 0; r < 4; ++r) {
      float m0 = fmaxf(fmaxf(sc[0][r], sc[1][r]), fmaxf(sc[2][r], sc[3][r]));
      float m1 = fmaxf(fmaxf(sc[4][r], sc[5][r]), fmaxf(sc[6][r], sc[7][r]));
      tmax[r] = fmaxf(m0, m1);
    }
    #pragma unroll
    for (int off = 1; off < 16; off <<= 1)
      #pragma unroll
      for (int r = 0; r < 4; ++r) tmax[r] = fmaxf(tmax[r], __shfl_xor(tmax[r], off));
    bool grow = (tmax[0] > mrow[0]) | (tmax[1] > mrow[1]) |
                (tmax[2] > mrow[2]) | (tmax[3] > mrow[3]);
    if (grow) {
      float alpha[4];
      #pragma unroll
      for (int r = 0; r < 4; ++r) {
        float mnew = fmaxf(mrow[r], tmax[r]);
        alpha[r] = exp2_hw(mrow[r] - mnew);
        mrow[r] = mnew;
        lrow[r] *= alpha[r];
      }
      #pragma unroll
      for (int cf = 0; cf < 4; ++cf)
        #pragma unroll
        for (int r = 0; r < 4; ++r) osum[cf][r] *= alpha[r];
    }
    char* pw = pp + wave * 4096;
    float psum[4] = {0.f, 0.f, 0.f, 0.f};
    #pragma unroll
    for (int sf = 0; sf < 8; ++sf) {
      int s = sf * 16 + r15;
      int chunk = s >> 3;
      #pragma unroll
      for (int r = 0; r < 4; ++r) {
        float p = exp2_hw(sc[sf][r] - mrow[r]);
        psum[r] += p;
        int tlc = l4 * 4 + r;
        *reinterpret_cast<__hip_bfloat16*>(pw + tlc * 256 + (((chunk ^ (tlc & 15)) << 4) | ((s & 7) * 2)))
            = __float2bfloat16(p);
      }
    }
    #pragma unroll
    for (int r = 0; r < 4; ++r) lrow[r] += psum[r];
    asm volatile("s_waitcnt lgkmcnt(0)" ::: "memory");
    __builtin_amdgcn_sched_barrier(0);

    bf16x8 pa[4];
    #pragma unroll
    for (int kk2 = 0; kk2 < 4; ++kk2)
      pa[kk2] = *reinterpret_cast<const bf16x8*>(pw + r15 * 256 + (((kk2 * 4 + l4) ^ (r15 & 15)) << 4));
    __builtin_amdgcn_s_setprio(1);
    #pragma unroll
    for (int cf = 0; cf < 4; ++cf) {
      int cr = cf * 16 + r15;
      #pragma unroll
      for (int kk2 = 0; kk2 < 4; ++kk2) {
        bf16x8 bv = *reinterpret_cast<const bf16x8*>(vcur + (kk2 >> 1) * 8192 + cr * 128 +
                                                     ((((kk2 & 1) * 4 + l4) ^ (cr & 7)) << 4));
        osum[cf] = __builtin_amdgcn_mfma_f32_16x16x32_bf16(pa[kk2], bv, osum[cf], 0, 0, 0);
      }
    }
    __builtin_amdgcn_s_setprio(0);
    __syncthreads();
  }

  #pragma unroll
  for (int off = 1; off < 16; off <<= 1)
    #pragma unroll
    for (int r = 0; r < 4; ++r) lrow[r] += __shfl_xor(lrow[r], off);
  float linv[4];
  #pragma unroll
  for (int r = 0; r < 4; ++r) linv[r] = 1.f / lrow[r];

  #pragma unroll
  for (int cf = 0; cf < 4; ++cf) {
    int c = cf * 16 + r15;
    #pragma unroll
    for (int r = 0; r < 4; ++r) {
      int t = qt * 64 + qw * 16 + l4 * 4 + r;
      *reinterpret_cast<__hip_bfloat16*>(ov + t * 128 + ((((c >> 3) ^ (t & 7)) << 4) | ((c & 7) * 2)))
          = __float2bfloat16(osum[cf][r] * linv[r]);
    }
  }
  __syncthreads();
  __hip_bfloat16* ap = aT + ((size_t)b * 1056 + 16 + blockIdx.x * 256) * 512 + hd * 64;
  for (int u = TID; u < 2048; u += 1024) {
    int t = u >> 3, cj = u & 7;
    uint4 o4 = *reinterpret_cast<const uint4*>(ov + t * 128 + ((cj ^ (t & 7)) << 4));
    *reinterpret_cast<uint4*>(ap + (size_t)t * 512 + cj * 8) = o4;
  }
}

// ---------------- final: out = x + mish(gn(y2)) in-place on d_out (raw stats) ----------------
__global__ __launch_bounds__(256) void final_kernel(const float* __restrict__ x,
    float* __restrict__ y, const float* __restrict__ straw,
    const float* __restrict__ w, const float* __restrict__ bv) {
  size_t i = ((size_t)blockIdx.x * 256 + TID) * 4;
  int ch = (int)((i >> 10) & (Cc - 1));
  int b = (int)(i >> 19);
  int g = b * 8 + (ch >> 6);
  float rs = straw[2 * g], rq = straw[2 * g + 1];
  float mean = rs * (1.f / 65536.f);
  float rstd = rsqrtf(fmaxf(rq * (1.f / 65536.f) - mean * mean, 0.f) + 1e-5f);
  float sw = w[ch] * rstd;
  float sb = bv[ch] - mean * sw;
  float4 v  = *reinterpret_cast<const float4*>(y + i);
  float4 xv = *reinterpret_cast<const float4*>(x + i);
  v.x = xv.x + mishf(v.x * sw + sb);
  v.y = xv.y + mishf(v.y * sw + sb);
  v.z = xv.z + mishf(v.z * sw + sb);
  v.w = xv.w + mishf(v.w * sw + sb);
  *reinterpret_cast<float4*>(y + i) = v;
}

extern "C" void kernel_launch(void* const* d_in, const int* in_sizes, int n_in,
                              void* d_out, int out_size, void* d_ws, size_t ws_size,
                              hipStream_t stream) {
  const float* x     = (const float*)d_in[0];
  const float* gn_w  = (const float*)d_in[1];
  const float* gn_b  = (const float*)d_in[2];
  const float* wqkv  = (const float*)d_in[3];
  const float* bqkv  = (const float*)d_in[4];
  const float* gnq_w = (const float*)d_in[5];
  const float* gnq_b = (const float*)d_in[6];
  const float* wproj = (const float*)d_in[7];
  const float* bproj = (const float*)d_in[8];
  const float* gnp_w = (const float*)d_in[9];
  const float* gnp_b = (const float*)d_in[10];
  float* out = (float*)d_out;

  char* ws = (char*)d_ws;
  const size_t MB = 1024 * 1024;
  __hip_bfloat16* qkvb = (__hip_bfloat16*)ws;            // [0,24MB)   step3 -> step4
  __hip_bfloat16* aT   = (__hip_bfloat16*)(ws + 24 * MB);// [24,33MB)  step1/5 -> step6 (padded)
  __hip_bfloat16* A1s  = (__hip_bfloat16*)(ws + 40 * MB);// [40,43MB)  step1 -> step3
  __hip_bfloat16* A2   = (__hip_bfloat16*)(ws + 44 * MB);// [44,46MB)  step1 -> step6
  char* vimg = ws + 56 * MB;                             // [56,64MB)  step4 -> step5
  float* st2raw = (float*)(ws + 64 * MB);
  float* st3raw = st2raw + 128;
  __hip_bfloat16* hT = (__hip_bfloat16*)d_out;           // d_out[0,8.44MB) step1/2 -> step3
  char* qTp  = (char*)d_out;                             // d_out[0,8MB)  step4 -> step5
  char* kimg = (char*)d_out + 8 * MB;                    // d_out[8,16MB) step4 -> step5

  dim3 blk(256);
  prep_misc<<<2177, blk, 0, stream>>>(wqkv, wproj, A1s, A2, aT, hT, st2raw);        // 1
  gn1_hT<<<256, blk, 0, stream>>>(x, gn_w, gn_b, hT);                               // 2
  gemm_s2<<<256, dim3(1024), 0, stream>>>(A1s, hT, bqkv, qkvb, st2raw);             // 3
  gn2_prep<<<1024, blk, 0, stream>>>(qkvb, st2raw, gnq_w, gnq_b, qTp, kimg, vimg);  // 4
  attn_mfma6<<<dim3(4, 64), dim3(1024), 0, stream>>>(qTp, kimg, vimg, aT);          // 5
  gemm_c4d<<<256, blk, 0, stream>>>(A2, aT, bproj, out, st3raw);                    // 6
  final_kernel<<<4096, blk, 0, stream>>>(x, out, st3raw, gnp_w, gnp_b);             // 7
}

// Round 23
// 139.948 us; speedup vs baseline: 1.4222x; 1.0292x over previous
//
#include <hip/hip_runtime.h>
#include <hip/hip_bf16.h>
#include <math.h>

#define TID threadIdx.x

constexpr int Cc = 512, Tt = 1024, C3 = 1536;

typedef __attribute__((ext_vector_type(8))) __bf16 bf16x8;
typedef __attribute__((ext_vector_type(4))) float f32x4;

__device__ __forceinline__ void async16(const void* g, void* l) {
  __builtin_amdgcn_global_load_lds(
      (const __attribute__((address_space(1))) unsigned int*)g,
      (__attribute__((address_space(3))) unsigned int*)l, 16, 0, 0);
}

__device__ __forceinline__ unsigned int pack2bf(float a, float b) {
  __hip_bfloat162 h;
  h.x = __float2bfloat16(a);
  h.y = __float2bfloat16(b);
  return *reinterpret_cast<unsigned int*>(&h);
}

__device__ __forceinline__ float bf2f(unsigned short u) {
  unsigned int t = ((unsigned int)u) << 16;
  union { unsigned int i; float f; } c;
  c.i = t;
  return c.f;
}

// hardware 2^x (v_exp_f32: D = 2^S0)
__device__ __forceinline__ float exp2_hw(float x) {
  float r;
  asm("v_exp_f32 %0, %1" : "=v"(r) : "v"(x));
  return r;
}

// mish(x) = x * n/(n+2), n = u*(u+2), u = e^x  (one hw exp + one rcp)
__device__ __forceinline__ float mishf(float x) {
  float u = __expf(x);
  float n = u * (u + 2.f);
  float r = x * n * __builtin_amdgcn_rcpf(n + 2.f);
  return (x > 20.f) ? x : r;
}

__device__ __forceinline__ void blockReduce2(float& s, float& ss) {
  #pragma unroll
  for (int off = 32; off > 0; off >>= 1) {
    s  += __shfl_xor(s,  off);
    ss += __shfl_xor(ss, off);
  }
  __shared__ float ls[4], lss[4];
  int w = TID >> 6;
  if ((TID & 63) == 0) { ls[w] = s; lss[w] = ss; }
  __syncthreads();
  s  = ls[0] + ls[1] + ls[2] + ls[3];
  ss = lss[0] + lss[1] + lss[2] + lss[3];
}

// ---------------- fused misc prep: weight casts + zero stats ----------------
// blocks [0,1536): cast_wqkv | [1536,2048): cast_wproj | 2048: zero stats(256 floats)
__global__ __launch_bounds__(256) void prep_misc(const float* __restrict__ wq,
    const float* __restrict__ wp, __hip_bfloat16* __restrict__ A1s,
    __hip_bfloat16* __restrict__ A2, float* __restrict__ stats) {
  int bid = blockIdx.x;
  if (bid < 1536) {
    int o = bid;
    int ci = TID * 2;
    float4 v = *reinterpret_cast<const float4*>(wq + ((size_t)o * 512 + ci) * 2);
    unsigned int u0 = pack2bf(v.x, v.z);
    unsigned int u1 = pack2bf(v.y, v.w);
    *reinterpret_cast<unsigned int*>(A1s + (size_t)o * 512 + ci) = u0;
    *reinterpret_cast<unsigned int*>(A1s + ((size_t)1536 + o) * 512 + ci) = u1;
  } else if (bid < 2048) {
    int o = bid - 1536;
    int ci = TID * 2;
    float4 v0 = *reinterpret_cast<const float4*>(wp + ((size_t)o * 512 + ci) * 4);
    float4 v1 = *reinterpret_cast<const float4*>(wp + ((size_t)o * 512 + ci + 1) * 4);
    const float* a0 = &v0.x;
    const float* a1 = &v1.x;
    #pragma unroll
    for (int j = 0; j < 4; ++j) {
      unsigned int u = pack2bf(a0[j], a1[j]);
      *reinterpret_cast<unsigned int*>(A2 + ((size_t)j * 512 + o) * 512 + ci) = u;
    }
  } else {
    stats[TID] = 0.f;
  }
}

// ---------------- fused GN(32) -> bf16 hT[b][16+t][ci], SINGLE-PASS (x read once via LDS) ----
// Also zeroes its own 16-channel slice of the hT halo pads.
__global__ __launch_bounds__(256) void gn1_hT(const float* __restrict__ x,
    const float* __restrict__ w, const float* __restrict__ bv,
    __hip_bfloat16* __restrict__ hT) {
  __shared__ float xs[16][1026];   // 64KB + pad(+2) against column-read conflicts
  int blk = blockIdx.x, bb = blk >> 5, g = blk & 31;
  size_t base = ((size_t)bb * Cc + g * 16) * Tt;
  const float* xp = x + base;
  float s = 0.f, ss = 0.f;
  for (int i = TID * 4; i < 16 * Tt; i += 1024) {
    int row = i >> 10, col = i & 1023;
    float4 v = *reinterpret_cast<const float4*>(xp + i);
    xs[row][col + 0] = v.x;
    xs[row][col + 1] = v.y;
    xs[row][col + 2] = v.z;
    xs[row][col + 3] = v.w;
    s  += v.x + v.y + v.z + v.w;
    ss += v.x * v.x + v.y * v.y + v.z * v.z + v.w * v.w;
  }
  blockReduce2(s, ss);   // internal barrier also fences the xs writes
  float mean = s * (1.f / 16384.f);
  float rstd = rsqrtf(ss * (1.f / 16384.f) - mean * mean + 1e-5f);

  __hip_bfloat16* ob = hT + (size_t)bb * 1056 * 512 + g * 16;
  // zero this block's slice of the halo pads (rows 0..15 and 1040..1055, 16 channels)
  if (TID < 64) {
    int pr = TID >> 1, c0 = (TID & 1) * 8;
    int P = (pr < 16) ? pr : (1024 + pr);
    uint4 z = {0u, 0u, 0u, 0u};
    *reinterpret_cast<uint4*>(hT + ((size_t)bb * 1056 + P) * 512 + g * 16 + c0) = z;
  }
  // normalize + pack + store (c0 constant per thread: precompute 8 sw/sb)
  int c0 = (TID & 1) * 8;
  float swv[8], sbv[8];
  #pragma unroll
  for (int k = 0; k < 8; ++k) {
    int ch = g * 16 + c0 + k;
    swv[k] = w[ch] * rstd;
    sbv[k] = bv[ch] - mean * swv[k];
  }
  for (int task = TID; task < 2048; task += 256) {
    int t = task >> 1;
    uint4 u;
    u.x = pack2bf(xs[c0 + 0][t] * swv[0] + sbv[0], xs[c0 + 1][t] * swv[1] + sbv[1]);
    u.y = pack2bf(xs[c0 + 2][t] * swv[2] + sbv[2], xs[c0 + 3][t] * swv[3] + sbv[3]);
    u.z = pack2bf(xs[c0 + 4][t] * swv[4] + sbv[4], xs[c0 + 5][t] * swv[5] + sbv[5]);
    u.w = pack2bf(xs[c0 + 6][t] * swv[6] + sbv[6], xs[c0 + 7][t] * swv[7] + sbv[7]);
    *reinterpret_cast<uint4*>(ob + (size_t)(16 + t) * 512 + c0) = u;
  }
}

// ---------------- shift-conv GEMM for conv K=2 (gemm1): BM=192 x BN=256, 1024 thr (R21-proven) --
__global__ __launch_bounds__(1024, 4) void gemm_s2(const __hip_bfloat16* __restrict__ A1s,
    const __hip_bfloat16* __restrict__ hT, const float* __restrict__ bias,
    __hip_bfloat16* __restrict__ Cout, float* __restrict__ statraw) {
  constexpr int BUF = 41 * 1024;
  __shared__ __align__(16) char lds[2 * BUF];
  int bz = blockIdx.x & 7;
  int inner = blockIdx.x >> 3;
  int t0 = (inner & 3) * 256;
  int og = inner >> 2;
  int o0 = og * 192;
  int wave = TID >> 6, lane = TID & 63;
  int l4 = lane >> 4, r15 = lane & 15;
  int wm = wave >> 2, wn = wave & 3;
  const __hip_bfloat16* hTb = hT + (size_t)bz * 1056 * 512;

  f32x4 acc[3][4];
  f32x4 zz = {0.f, 0.f, 0.f, 0.f};
  #pragma unroll
  for (int m = 0; m < 3; ++m)
    #pragma unroll
    for (int n = 0; n < 4; ++n) acc[m][n] = zz;

  auto stage = [&](int kt, int buf) {
    char* dst = lds + buf * BUF;
    #pragma unroll
    for (int c = 0; c < 3; ++c) {
      int ch = c * 16 + wave;
      if (ch < 41) {
        const __hip_bfloat16* src;
        if (ch < 24) {
          int j = (ch >= 12) ? 1 : 0;
          int rg = ch - j * 12;
          src = A1s + ((size_t)j * 1536 + o0 + rg * 16 + r15) * 512 + kt * 32 + l4 * 8;
        } else {
          int rg = ch - 24;
          src = hTb + (size_t)(16 + t0 + rg * 16 + r15) * 512 + kt * 32 + l4 * 8;
        }
        async16(src, dst + ch * 1024 + lane * 16);
      }
    }
  };

  stage(0, 0);
  __syncthreads();
  for (int kt = 0; kt < 16; ++kt) {
    if (kt + 1 < 16) stage(kt + 1, (kt + 1) & 1);
    char* cur = lds + (kt & 1) * BUF;
    #pragma unroll
    for (int j = 0; j < 2; ++j) {
      bf16x8 af[3], bfr[4];
      #pragma unroll
      for (int m = 0; m < 3; ++m)
        af[m] = *reinterpret_cast<const bf16x8*>(cur + (j * 12 + wm * 3 + m) * 1024 + lane * 16);
      #pragma unroll
      for (int n = 0; n < 4; ++n) {
        int q = (wn * 4 + n) * 16 + r15 + j;
        bfr[n] = *reinterpret_cast<const bf16x8*>(cur + 24 * 1024 + (q >> 4) * 1024 + l4 * 256 + (q & 15) * 16);
      }
      #pragma unroll
      for (int m = 0; m < 3; ++m)
        #pragma unroll
        for (int n = 0; n < 4; ++n)
          acc[m][n] = __builtin_amdgcn_mfma_f32_16x16x32_bf16(af[m], bfr[n], acc[m][n], 0, 0, 0);
    }
    __syncthreads();
  }

  float* sred = reinterpret_cast<float*>(lds);
  #pragma unroll
  for (int m = 0; m < 3; ++m) {
    float s = 0.f, ss2 = 0.f;
    #pragma unroll
    for (int n = 0; n < 4; ++n) {
      int ocol = t0 + (wn * 4 + n) * 16 + r15;
      #pragma unroll
      for (int r = 0; r < 4; ++r) {
        int orow = o0 + (wm * 3 + m) * 16 + l4 * 4 + r;
        float v = acc[m][n][r] + bias[orow];
        Cout[((size_t)bz * C3 + orow) * 1024 + ocol] = __float2bfloat16(v);
        s += v;
        ss2 += v * v;
      }
    }
    #pragma unroll
    for (int off = 1; off < 64; off <<= 1) {
      s   += __shfl_xor(s, off);
      ss2 += __shfl_xor(ss2, off);
    }
    if (lane == 0) {
      sred[(wave * 3 + m) * 2]     = s;
      sred[(wave * 3 + m) * 2 + 1] = ss2;
    }
  }
  __syncthreads();
  if (TID == 0) {
    float S = 0.f, SS = 0.f;
    #pragma unroll
    for (int slot = 0; slot < 48; ++slot) {
      S  += sred[slot * 2];
      SS += sred[slot * 2 + 1];
    }
    int g = bz * 8 + og;
    atomicAdd(&statraw[2 * g],     S);
    atomicAdd(&statraw[2 * g + 1], SS);
  }
}

// ---------------- shift-conv GEMM (conv K=4) v2: BM=64 x BN=256, 256 thr (R22-proven) ----
__global__ __launch_bounds__(256) void gemm_c4d(const __hip_bfloat16* __restrict__ A2,
    const __hip_bfloat16* __restrict__ aT, const float* __restrict__ bias,
    float* __restrict__ Cout, float* __restrict__ statraw) {
  constexpr int BUF = 34 * 1024;
  __shared__ __align__(16) char lds[2 * BUF];
  int bz = blockIdx.x & 7;
  int inner = blockIdx.x >> 3;
  int t0 = (inner & 3) * 256;
  int o0 = (inner >> 2) * 64;
  int wave = TID >> 6, lane = TID & 63;
  int l4 = lane >> 4, r15 = lane & 15;
  const __hip_bfloat16* aTb = aT + (size_t)bz * 1056 * 512;

  f32x4 acc[4][4];
  f32x4 zz = {0.f, 0.f, 0.f, 0.f};
  #pragma unroll
  for (int m = 0; m < 4; ++m)
    #pragma unroll
    for (int n = 0; n < 4; ++n) acc[m][n] = zz;

  auto stage = [&](int kt, int buf) {
    char* dst = lds + buf * BUF;
    #pragma unroll
    for (int c = 0; c < 9; ++c) {
      int ch = c * 4 + wave;
      if (ch < 34) {
        const __hip_bfloat16* src;
        if (ch < 16) {
          int j = ch >> 2, rg = ch & 3;
          src = A2 + ((size_t)j * 512 + o0 + rg * 16 + r15) * 512 + kt * 32 + l4 * 8;
        } else {
          int rg = ch - 16;
          src = aTb + (size_t)(t0 + rg * 16 + r15) * 512 + kt * 32 + l4 * 8;
        }
        async16(src, dst + ch * 1024 + lane * 16);
      }
    }
  };

  stage(0, 0);
  __syncthreads();
  for (int kt = 0; kt < 16; ++kt) {
    if (kt + 1 < 16) stage(kt + 1, (kt + 1) & 1);
    char* cur = lds + (kt & 1) * BUF;
    #pragma unroll
    for (int j = 0; j < 4; ++j) {
      bf16x8 af[4], bfr[4];
      #pragma unroll
      for (int m = 0; m < 4; ++m)
        af[m] = *reinterpret_cast<const bf16x8*>(cur + (j * 4 + m) * 1024 + lane * 16);
      #pragma unroll
      for (int n = 0; n < 4; ++n) {
        int q = (wave * 4 + n) * 16 + r15 + j + 15;
        bfr[n] = *reinterpret_cast<const bf16x8*>(cur + 16 * 1024 + (q >> 4) * 1024 + l4 * 256 + (q & 15) * 16);
      }
      #pragma unroll
      for (int m = 0; m < 4; ++m)
        #pragma unroll
        for (int n = 0; n < 4; ++n)
          acc[m][n] = __builtin_amdgcn_mfma_f32_16x16x32_bf16(af[m], bfr[n], acc[m][n], 0, 0, 0);
    }
    __syncthreads();
  }

  float* sred = reinterpret_cast<float*>(lds);
  #pragma unroll
  for (int m = 0; m < 4; ++m) {
    float s = 0.f, ss2 = 0.f;
    #pragma unroll
    for (int n = 0; n < 4; ++n) {
      int ocol = t0 + (wave * 4 + n) * 16 + r15;
      #pragma unroll
      for (int r = 0; r < 4; ++r) {
        int orow = o0 + m * 16 + l4 * 4 + r;
        float v = acc[m][n][r] + bias[orow];
        Cout[((size_t)bz * Cc + orow) * 1024 + ocol] = v;
        s += v;
        ss2 += v * v;
      }
    }
    #pragma unroll
    for (int off = 1; off < 64; off <<= 1) {
      s   += __shfl_xor(s, off);
      ss2 += __shfl_xor(ss2, off);
    }
    if (lane == 0) {
      sred[(wave * 4 + m) * 2]     = s;
      sred[(wave * 4 + m) * 2 + 1] = ss2;
    }
  }
  __syncthreads();
  if (TID == 0) {
    float S = 0.f, SS = 0.f;
    #pragma unroll
    for (int slot = 0; slot < 16; ++slot) {
      S  += sred[slot * 2];
      SS += sred[slot * 2 + 1];
    }
    int g = bz * 8 + (o0 >> 6);
    atomicAdd(&statraw[2 * g],     S);
    atomicAdd(&statraw[2 * g + 1], SS);
  }
}

// ---------------- fused GN(8)+Mish + build attn input images (bf16 qkv input, raw stats) ----------------
__global__ __launch_bounds__(256) void gn2_prep(const __hip_bfloat16* __restrict__ qkv,
    const float* __restrict__ straw, const float* __restrict__ w, const float* __restrict__ bv,
    char* __restrict__ qTp, char* __restrict__ kimg, char* __restrict__ vimg) {
  __shared__ unsigned short hbf[192 * 66];
  int tl = blockIdx.x & 15, hb = blockIdx.x >> 4;
  int b = hb >> 3, hd = hb & 7;
  float rs = straw[2 * (b * 8 + hd)], rq = straw[2 * (b * 8 + hd) + 1];
  float mean = rs * (1.f / 196608.f);
  float rstd = rsqrtf(fmaxf(rq * (1.f / 196608.f) - mean * mean, 0.f) + 1e-5f);
  for (int task = TID; task < 768; task += 256) {
    int row = task >> 2, seg = task & 3;
    int ch = hd * 192 + row;
    float sw = w[ch] * rstd;
    float sb = bv[ch] - mean * sw;
    const uint4* src = reinterpret_cast<const uint4*>(
        qkv + ((size_t)(b * C3 + ch)) * 1024 + tl * 64 + seg * 16);
    uint4 u0 = src[0], u1 = src[1];
    unsigned int uu[8] = {u0.x, u0.y, u0.z, u0.w, u1.x, u1.y, u1.z, u1.w};
    unsigned int* dst = reinterpret_cast<unsigned int*>(&hbf[row * 66 + seg * 16]);
    #pragma unroll
    for (int j = 0; j < 8; ++j) {
      float a = mishf(bf2f((unsigned short)(uu[j] & 0xffff)) * sw + sb);
      float c = mishf(bf2f((unsigned short)(uu[j] >> 16)) * sw + sb);
      dst[j] = pack2bf(a, c);
    }
  }
  __syncthreads();
  size_t tileof = ((size_t)hb * 16 + tl) * 8192;
  {
    int t = TID & 63, sel = TID >> 6;
    int img = sel >> 1, half = sel & 1;
    char* obase = (img == 0 ? qTp : kimg) + tileof + (size_t)t * 128;
    #pragma unroll
    for (int cc = 0; cc < 4; ++cc) {
      int chunk = half * 4 + cc;
      uint4 u;
      unsigned int* up = reinterpret_cast<unsigned int*>(&u);
      #pragma unroll
      for (int j = 0; j < 4; ++j) {
        int c = chunk * 8 + j * 2;
        unsigned int lo = hbf[(img * 64 + c) * 66 + t];
        unsigned int hi = hbf[(img * 64 + c + 1) * 66 + t];
        up[j] = lo | (hi << 16);
      }
      int cpos = (img == 0) ? chunk : (chunk ^ (t & 7));
      *reinterpret_cast<uint4*>(obase + cpos * 16) = u;
    }
  }
  {
    int c = TID & 63, qtr = TID >> 6;
    const unsigned int* vrow = reinterpret_cast<const unsigned int*>(&hbf[(128 + c) * 66]);
    char* obase = vimg + tileof + (size_t)c * 128;
    #pragma unroll
    for (int k = 0; k < 2; ++k) {
      int chunk = qtr * 2 + k;
      uint4 u;
      unsigned int* up = reinterpret_cast<unsigned int*>(&u);
      #pragma unroll
      for (int j = 0; j < 4; ++j) up[j] = vrow[chunk * 4 + j];
      *reinterpret_cast<uint4*>(obase + (chunk ^ (c & 7)) * 16) = u;
    }
  }
}

// ---------------- MFMA flash attention v6: KVBLK=128 + setprio; zeroes its own aT pads ----------------
__global__ __launch_bounds__(1024) void attn_mfma6(const char* __restrict__ qTp,
    const char* __restrict__ kimg, const char* __restrict__ vimg,
    __hip_bfloat16* __restrict__ aT) {
  __shared__ __align__(16) char smem[131072];
  char* kbuf0 = smem;
  char* kbuf1 = smem + 16384;
  char* vbuf0 = smem + 32768;
  char* vbuf1 = smem + 49152;
  char* pp    = smem + 65536;  // 16 waves x 4KB
  char* ov    = smem;          // 32KB alias (dead K/V buffers)

  int hb = blockIdx.y;
  int b = hb >> 3, hd = hb & 7;
  int lane = TID & 63, wave = TID >> 6;
  int qt = wave >> 2, qw = wave & 3;
  int l4 = lane >> 4, r15 = lane & 15;
  size_t ibase = (size_t)hb * 16 * 8192;
  const char* ksrc = kimg + ibase;
  const char* vsrc = vimg + ibase;

  async16(ksrc + (size_t)TID * 16, kbuf0 + (size_t)TID * 16);
  async16(vsrc + (size_t)TID * 16, vbuf0 + (size_t)TID * 16);

  // zero this head's aT halo pads (block 0: rows 0..15, block 3: rows 1040..1055)
  if ((blockIdx.x == 0 || blockIdx.x == 3) && TID < 128) {
    int pr = TID >> 3, cj = TID & 7;
    int P = (blockIdx.x == 0) ? pr : (1040 + pr);
    uint4 z = {0u, 0u, 0u, 0u};
    *reinterpret_cast<uint4*>(aT + ((size_t)b * 1056 + P) * 512 + hd * 64 + cj * 8) = z;
  }

  bf16x8 aq[2];
  int tg = qw * 16 + r15;
  const char* qrow = qTp + ibase + (size_t)(blockIdx.x * 4 + qt) * 8192 + (size_t)tg * 128;
  aq[0] = *reinterpret_cast<const bf16x8*>(qrow + l4 * 16);
  aq[1] = *reinterpret_cast<const bf16x8*>(qrow + 64 + l4 * 16);
  {
    const float SC = 0.125f * 1.44269504f;
    #pragma unroll
    for (int kk = 0; kk < 2; ++kk) {
      unsigned int* u = reinterpret_cast<unsigned int*>(&aq[kk]);
      #pragma unroll
      for (int j = 0; j < 4; ++j) {
        float lo = bf2f((unsigned short)(u[j] & 0xffff)) * SC;
        float hi = bf2f((unsigned short)(u[j] >> 16)) * SC;
        u[j] = pack2bf(lo, hi);
      }
    }
  }

  f32x4 osum[4];
  f32x4 zz = {0.f, 0.f, 0.f, 0.f};
  #pragma unroll
  for (int cf = 0; cf < 4; ++cf) osum[cf] = zz;
  float mrow[4] = {-1e30f, -1e30f, -1e30f, -1e30f};
  float lrow[4] = {0.f, 0.f, 0.f, 0.f};
  __syncthreads();

  for (int it = 0; it < 8; ++it) {
    char* kcur = (it & 1) ? kbuf1 : kbuf0;
    char* vcur = (it & 1) ? vbuf1 : vbuf0;
    if (it < 7) {
      char* knxt = (it & 1) ? kbuf0 : kbuf1;
      char* vnxt = (it & 1) ? vbuf0 : vbuf1;
      const char* kn = ksrc + (size_t)(it + 1) * 16384;
      const char* vn = vsrc + (size_t)(it + 1) * 16384;
      async16(kn + (size_t)TID * 16, knxt + (size_t)TID * 16);
      async16(vn + (size_t)TID * 16, vnxt + (size_t)TID * 16);
    }
    f32x4 sc[8];
    #pragma unroll
    for (int sf = 0; sf < 8; ++sf) sc[sf] = zz;
    __builtin_amdgcn_s_setprio(1);
    #pragma unroll
    for (int sf = 0; sf < 8; ++sf) {
      int sr = sf * 16 + r15;
      #pragma unroll
      for (int kk = 0; kk < 2; ++kk) {
        bf16x8 bk = *reinterpret_cast<const bf16x8*>(kcur + sr * 128 + (((kk * 4 + l4) ^ (sr & 7)) << 4));
        sc[sf] = __builtin_amdgcn_mfma_f32_16x16x32_bf16(aq[kk], bk, sc[sf], 0, 0, 0);
      }
    }
    __builtin_amdgcn_s_setprio(0);
    float tmax[4];
    #pragma unroll
    for (int r = 0; r < 4; ++r) {
      float m0 = fmaxf(fmaxf(sc[0][r], sc[1][r]), fmaxf(sc[2][r], sc[3][r]));
      float m1 = fmaxf(fmaxf(sc[4][r], sc[5][r]), fmaxf(sc[6][r], sc[7][r]));
      tmax[r] = fmaxf(m0, m1);
    }
    #pragma unroll
    for (int off = 1; off < 16; off <<= 1)
      #pragma unroll
      for (int r = 0; r < 4; ++r) tmax[r] = fmaxf(tmax[r], __shfl_xor(tmax[r], off));
    bool grow = (tmax[0] > mrow[0]) | (tmax[1] > mrow[1]) |
                (tmax[2] > mrow[2]) | (tmax[3] > mrow[3]);
    if (grow) {
      float alpha[4];
      #pragma unroll
      for (int r = 0; r < 4; ++r) {
        float mnew = fmaxf(mrow[r], tmax[r]);
        alpha[r] = exp2_hw(mrow[r] - mnew);
        mrow[r] = mnew;
        lrow[r] *= alpha[r];
      }
      #pragma unroll
      for (int cf = 0; cf < 4; ++cf)
        #pragma unroll
        for (int r = 0; r < 4; ++r) osum[cf][r] *= alpha[r];
    }
    char* pw = pp + wave * 4096;
    float psum[4] = {0.f, 0.f, 0.f, 0.f};
    #pragma unroll
    for (int sf = 0; sf < 8; ++sf) {
      int s = sf * 16 + r15;
      int chunk = s >> 3;
      #pragma unroll
      for (int r = 0; r < 4; ++r) {
        float p = exp2_hw(sc[sf][r] - mrow[r]);
        psum[r] += p;
        int tlc = l4 * 4 + r;
        *reinterpret_cast<__hip_bfloat16*>(pw + tlc * 256 + (((chunk ^ (tlc & 15)) << 4) | ((s & 7) * 2)))
            = __float2bfloat16(p);
      }
    }
    #pragma unroll
    for (int r = 0; r < 4; ++r) lrow[r] += psum[r];
    asm volatile("s_waitcnt lgkmcnt(0)" ::: "memory");
    __builtin_amdgcn_sched_barrier(0);

    bf16x8 pa[4];
    #pragma unroll
    for (int kk2 = 0; kk2 < 4; ++kk2)
      pa[kk2] = *reinterpret_cast<const bf16x8*>(pw + r15 * 256 + (((kk2 * 4 + l4) ^ (r15 & 15)) << 4));
    __builtin_amdgcn_s_setprio(1);
    #pragma unroll
    for (int cf = 0; cf < 4; ++cf) {
      int cr = cf * 16 + r15;
      #pragma unroll
      for (int kk2 = 0; kk2 < 4; ++kk2) {
        bf16x8 bv = *reinterpret_cast<const bf16x8*>(vcur + (kk2 >> 1) * 8192 + cr * 128 +
                                                     ((((kk2 & 1) * 4 + l4) ^ (cr & 7)) << 4));
        osum[cf] = __builtin_amdgcn_mfma_f32_16x16x32_bf16(pa[kk2], bv, osum[cf], 0, 0, 0);
      }
    }
    __builtin_amdgcn_s_setprio(0);
    __syncthreads();
  }

  #pragma unroll
  for (int off = 1; off < 16; off <<= 1)
    #pragma unroll
    for (int r = 0; r < 4; ++r) lrow[r] += __shfl_xor(lrow[r], off);
  float linv[4];
  #pragma unroll
  for (int r = 0; r < 4; ++r) linv[r] = 1.f / lrow[r];

  #pragma unroll
  for (int cf = 0; cf < 4; ++cf) {
    int c = cf * 16 + r15;
    #pragma unroll
    for (int r = 0; r < 4; ++r) {
      int t = qt * 64 + qw * 16 + l4 * 4 + r;
      *reinterpret_cast<__hip_bfloat16*>(ov + t * 128 + ((((c >> 3) ^ (t & 7)) << 4) | ((c & 7) * 2)))
          = __float2bfloat16(osum[cf][r] * linv[r]);
    }
  }
  __syncthreads();
  __hip_bfloat16* ap = aT + ((size_t)b * 1056 + 16 + blockIdx.x * 256) * 512 + hd * 64;
  for (int u = TID; u < 2048; u += 1024) {
    int t = u >> 3, cj = u & 7;
    uint4 o4 = *reinterpret_cast<const uint4*>(ov + t * 128 + ((cj ^ (t & 7)) << 4));
    *reinterpret_cast<uint4*>(ap + (size_t)t * 512 + cj * 8) = o4;
  }
}

// ---------------- final: out = x + mish(gn(y2)) in-place on d_out (raw stats) ----------------
__global__ __launch_bounds__(256) void final_kernel(const float* __restrict__ x,
    float* __restrict__ y, const float* __restrict__ straw,
    const float* __restrict__ w, const float* __restrict__ bv) {
  size_t i = ((size_t)blockIdx.x * 256 + TID) * 4;
  int ch = (int)((i >> 10) & (Cc - 1));
  int b = (int)(i >> 19);
  int g = b * 8 + (ch >> 6);
  float rs = straw[2 * g], rq = straw[2 * g + 1];
  float mean = rs * (1.f / 65536.f);
  float rstd = rsqrtf(fmaxf(rq * (1.f / 65536.f) - mean * mean, 0.f) + 1e-5f);
  float sw = w[ch] * rstd;
  float sb = bv[ch] - mean * sw;
  float4 v  = *reinterpret_cast<const float4*>(y + i);
  float4 xv = *reinterpret_cast<const float4*>(x + i);
  v.x = xv.x + mishf(v.x * sw + sb);
  v.y = xv.y + mishf(v.y * sw + sb);
  v.z = xv.z + mishf(v.z * sw + sb);
  v.w = xv.w + mishf(v.w * sw + sb);
  *reinterpret_cast<float4*>(y + i) = v;
}

extern "C" void kernel_launch(void* const* d_in, const int* in_sizes, int n_in,
                              void* d_out, int out_size, void* d_ws, size_t ws_size,
                              hipStream_t stream) {
  const float* x     = (const float*)d_in[0];
  const float* gn_w  = (const float*)d_in[1];
  const float* gn_b  = (const float*)d_in[2];
  const float* wqkv  = (const float*)d_in[3];
  const float* bqkv  = (const float*)d_in[4];
  const float* gnq_w = (const float*)d_in[5];
  const float* gnq_b = (const float*)d_in[6];
  const float* wproj = (const float*)d_in[7];
  const float* bproj = (const float*)d_in[8];
  const float* gnp_w = (const float*)d_in[9];
  const float* gnp_b = (const float*)d_in[10];
  float* out = (float*)d_out;

  char* ws = (char*)d_ws;
  const size_t MB = 1024 * 1024;
  __hip_bfloat16* qkvb = (__hip_bfloat16*)ws;            // [0,24MB)   step3 -> step4
  __hip_bfloat16* aT   = (__hip_bfloat16*)(ws + 24 * MB);// [24,33MB)  step5 -> step6 (padded; attn zeroes pads)
  __hip_bfloat16* A1s  = (__hip_bfloat16*)(ws + 40 * MB);// [40,43MB)  step1 -> step3
  __hip_bfloat16* A2   = (__hip_bfloat16*)(ws + 44 * MB);// [44,46MB)  step1 -> step6
  char* vimg = ws + 56 * MB;                             // [56,64MB)  step4 -> step5
  float* st2raw = (float*)(ws + 64 * MB);
  float* st3raw = st2raw + 128;
  __hip_bfloat16* hT = (__hip_bfloat16*)d_out;           // d_out[0,8.44MB) step2 -> step3 (gn1 zeroes pads)
  char* qTp  = (char*)d_out;                             // d_out[0,8MB)  step4 -> step5
  char* kimg = (char*)d_out + 8 * MB;                    // d_out[8,16MB) step4 -> step5

  dim3 blk(256);
  prep_misc<<<2049, blk, 0, stream>>>(wqkv, wproj, A1s, A2, st2raw);                // 1
  gn1_hT<<<256, blk, 0, stream>>>(x, gn_w, gn_b, hT);                               // 2
  gemm_s2<<<256, dim3(1024), 0, stream>>>(A1s, hT, bqkv, qkvb, st2raw);             // 3
  gn2_prep<<<1024, blk, 0, stream>>>(qkvb, st2raw, gnq_w, gnq_b, qTp, kimg, vimg);  // 4
  attn_mfma6<<<dim3(4, 64), dim3(1024), 0, stream>>>(qTp, kimg, vimg, aT);          // 5
  gemm_c4d<<<256, blk, 0, stream>>>(A2, aT, bproj, out, st3raw);                    // 6
  final_kernel<<<4096, blk, 0, stream>>>(x, out, st3raw, gnp_w, gnp_b);             // 7
}